// Round 8
// baseline (241.485 us; speedup 1.0000x reference)
//
#include <hip/hip_runtime.h>
#include <hip/hip_bf16.h>
#include <stdint.h>

#define B_   8
#define N_   4096
#define K1_  17
#define D_   256
#define NT_  (B_*N_)          // 32768
#define E16_ (NT_*16)         // 524288
#define NP_  (NT_*D_)         // 8388608
#define EPS_ 1e-5f

typedef __attribute__((ext_vector_type(8))) short short8v;  // 8 bf16 (4 VGPR)
typedef __attribute__((ext_vector_type(4))) short short4v;
typedef __attribute__((ext_vector_type(4))) float f32x4;

// f32 -> bf16 RNE, pure C
__device__ __forceinline__ unsigned short f2bfu(float f){
  unsigned u = __float_as_uint(f);
  unsigned r = (u + 0x7FFFu + ((u>>16)&1u)) >> 16;
  return (unsigned short)r;
}
__device__ __forceinline__ short f2bf(float f){ return (short)f2bfu(f); }
__device__ __forceinline__ unsigned pkbf(float lo, float hi){
  return (unsigned)f2bfu(lo) | ((unsigned)f2bfu(hi) << 16);
}
__device__ __forceinline__ float bf2f(short s){
  return __uint_as_float(((unsigned)(unsigned short)s) << 16);
}

// Wt swizzle (shared by writer k_cvt_w and the GEMM ds_read):
// short-index e=row*256+k  ->  e ^ ((row&7)<<3). XOR moves aligned 8-short
// (16B) groups, so uint4 copies stay linear; kills the 512B-row-stride
// bank conflict on B-fragment reads (G4 / rule #21: swizzle BOTH sides).
#define WSWZ(e, row) ((e) ^ (((row)&7)<<3))

// ---------------- edge-structure kernels ----------------

__global__ __launch_bounds__(256) void k_init(int* __restrict__ degcnt,
                                              const unsigned int* __restrict__ mw,
                                              int* __restrict__ flag){
  int i = blockIdx.x*256 + threadIdx.x;
  degcnt[i] = 0;
  if (blockIdx.x == 0){
    __shared__ int s_int, s_f32;
    if (threadIdx.x==0){ s_int=1; s_f32=1; }
    __syncthreads();
    int bad_i=0, bad_f=0;
    #pragma unroll
    for (int j=0;j<4;j++){
      unsigned w = mw[threadIdx.x*4 + j];
      if (!(w==0u || w==1u))          bad_i=1;
      if (!(w==0u || w==0x3F800000u)) bad_f=1;
    }
    if (bad_i) atomicAnd(&s_int, 0);
    if (bad_f) atomicAnd(&s_f32, 0);
    __syncthreads();
    if (threadIdx.x==0) *flag = s_int ? 0 : (s_f32 ? 1 : 2);
  }
}

__device__ __forceinline__ bool mask_at(const void* maskp, int f, int idx){
  if (f==0) return ((const int*)maskp)[idx] != 0;
  if (f==1) return ((const float*)maskp)[idx] != 0.0f;
  return ((const unsigned char*)maskp)[idx] != 0;
}

__global__ void k_deg(const int* __restrict__ knn, const void* __restrict__ maskp,
                      const int* __restrict__ flag, int* __restrict__ degcnt){
  int f = *flag;
  int e = blockIdx.x*blockDim.x + threadIdx.x;
  if (e >= E16_) return;
  int node = e >> 4;
  int k    = (e & 15) + 1;
  int idx  = node*K1_ + k;
  if (mask_at(maskp, f, idx)){
    int b   = node >> 12;
    int dst = knn[idx] + (b<<12);
    atomicAdd(&degcnt[dst], 1);
  }
}

__global__ void k_scan(const int* __restrict__ degcnt, int* __restrict__ rowptr,
                       int* __restrict__ fillptr, float* __restrict__ dinv){
  __shared__ int sm[1024];
  int t = threadIdx.x;
  int base = t*32;
  int loc[32]; int tot = 0;
  #pragma unroll
  for (int i=0;i<32;i++){ loc[i] = degcnt[base+i]; tot += loc[i]; }
  sm[t] = tot; __syncthreads();
  for (int off=1; off<1024; off<<=1){
    int v = (t>=off) ? sm[t-off] : 0;
    __syncthreads();
    sm[t] += v;
    __syncthreads();
  }
  int run = sm[t] - tot;
  #pragma unroll
  for (int i=0;i<32;i++){
    int v = base+i;
    rowptr[v]  = run;
    fillptr[v] = run;
    dinv[v]    = rsqrtf((float)loc[i] + 1.0f);
    run += loc[i];
  }
  if (t==1023) rowptr[NT_] = run;
}

__global__ void k_fill(const int* __restrict__ knn, const void* __restrict__ maskp,
                       const int* __restrict__ flag, int* __restrict__ fillptr,
                       int* __restrict__ col){
  int f = *flag;
  int e = blockIdx.x*blockDim.x + threadIdx.x;
  if (e >= E16_) return;
  int node = e >> 4;
  int k    = (e & 15) + 1;
  int idx  = node*K1_ + k;
  if (mask_at(maskp, f, idx)){
    int b   = node >> 12;
    int dst = knn[idx] + (b<<12);
    int pos = atomicAdd(&fillptr[dst], 1);
    col[pos] = node;
  }
}

// ---------------- weight transpose (both layers, LDS-tiled, swizzled out) ---
// 128 blocks: even -> W0, odd -> W1; tile = 32x32. Wt[swz(n,k)] = bf16(W[k][n]).
__global__ __launch_bounds__(256) void k_cvt_w(const float* __restrict__ W0,
                                               const float* __restrict__ W1,
                                               short* __restrict__ Wt0,
                                               short* __restrict__ Wt1){
  const float* W  = (blockIdx.x & 1) ? W1  : W0;
  short*       Wt = (blockIdx.x & 1) ? Wt1 : Wt0;
  int tile = blockIdx.x >> 1;
  int ti = tile >> 3, tj = tile & 7;      // ti: k-tile, tj: n-tile
  __shared__ float sm[32][33];
  int r = threadIdx.x >> 5, c = threadIdx.x & 31;
  #pragma unroll
  for (int i=0;i<4;i++)
    sm[r + i*8][c] = W[(ti*32 + r + i*8)*256 + tj*32 + c];
  __syncthreads();
  #pragma unroll
  for (int i=0;i<4;i++){
    int row = tj*32 + r + i*8;            // output col (n)
    int k   = ti*32 + c;
    int e   = row*256 + k;
    Wt[WSWZ(e, row)] = f2bf(sm[c][r + i*8]);
  }
}

// ---------------- MFMA GEMM, B staged in LDS (m97 structure) ----------------
// Block = 512 thr (8 waves) = 128 rows x 128 cols of C. Stage the 64KB Wt
// half-tile (swizzled layout, linear uint4 copy) into LDS once; each wave owns
// one 16-col strip and walks 8 row-tiles: 8 A global loads + 8 ds_read_b128
// (B-frags, swizzle-conflict-free) + 8 MFMA per tile. 2 blocks/CU (128KB LDS).
// XCD chunking: lb = (bid&7)*64 + bid>>3; rowblk = lb>>1 (col-half pairs share
// A rows on one XCD; each XCD's rows = one batch = 4MB f32 = L2-resident).
// A frag: lane l holds row row0+(l&15), elems ks*32 + 8*(l>>4) + j
// B frag: lane l holds Wt[colbase+(l&15)][ks*32 + 8*(l>>4) + j]  (from LDS)
// D frag: lane l reg r -> C[row0 + 4*(l>>4)+r][colbase + (l&15)]

// layer 0: A read from x (f32, row stride 512), converted in-register
__global__ __launch_bounds__(512, 4) void k_gemm_x(const float* __restrict__ X,
                                                   const short* __restrict__ Wt,
                                                   short* __restrict__ Ab){
  __shared__ short ldsW[128*256];          // 64KB, swizzled layout
  int lb     = (int)(blockIdx.x & 7)*64 + (int)(blockIdx.x >> 3);
  int rowblk = lb >> 1, half = lb & 1;
  {
    const uint4* src = (const uint4*)(Wt + half*128*256);
    uint4* dst = (uint4*)ldsW;
    #pragma unroll
    for (int i=0;i<8;i++) dst[threadIdx.x + i*512] = src[threadIdx.x + i*512];
  }
  __syncthreads();

  int wave = threadIdx.x >> 6;
  int lane = threadIdx.x & 63;
  int lr   = lane & 15;
  int qg   = lane >> 4;
  int rowB = rowblk*128;
  int rloc = wave*16 + lr;                 // local B row = local output col

  for (int rt=0; rt<8; rt++){
    int row0 = rowB + rt*16;
    const float* aRow = X + (size_t)(row0 + lr)*512 + qg*8;
    f32x4 acc = (f32x4){0.f,0.f,0.f,0.f};
    #pragma unroll
    for (int ks=0; ks<8; ks++){
      f32x4 p0 = *(const f32x4*)(aRow + ks*32);
      f32x4 p1 = *(const f32x4*)(aRow + ks*32 + 4);
      union { unsigned u[4]; short8v v; } cv;
      cv.u[0] = pkbf(p0[0], p0[1]);
      cv.u[1] = pkbf(p0[2], p0[3]);
      cv.u[2] = pkbf(p1[0], p1[1]);
      cv.u[3] = pkbf(p1[2], p1[3]);
      int e = rloc*256 + ks*32 + qg*8;
      short8v b = *(const short8v*)(ldsW + WSWZ(e, rloc));
      acc = __builtin_amdgcn_mfma_f32_16x16x32_bf16(cv.v, b, acc, 0, 0, 0);
    }
    int mrow = row0 + qg*4;
    int cout = half*128 + wave*16 + lr;
    #pragma unroll
    for (int r=0;r<4;r++)
      Ab[(size_t)(mrow + r)*256 + cout] = f2bf(acc[r]);
  }
}

// layer 1: A read from Hb (bf16, row stride 256)
__global__ __launch_bounds__(512, 4) void k_gemm_h(const short* __restrict__ Hb,
                                                   const short* __restrict__ Wt,
                                                   short* __restrict__ Ab){
  __shared__ short ldsW[128*256];          // 64KB, swizzled layout
  int lb     = (int)(blockIdx.x & 7)*64 + (int)(blockIdx.x >> 3);
  int rowblk = lb >> 1, half = lb & 1;
  {
    const uint4* src = (const uint4*)(Wt + half*128*256);
    uint4* dst = (uint4*)ldsW;
    #pragma unroll
    for (int i=0;i<8;i++) dst[threadIdx.x + i*512] = src[threadIdx.x + i*512];
  }
  __syncthreads();

  int wave = threadIdx.x >> 6;
  int lane = threadIdx.x & 63;
  int lr   = lane & 15;
  int qg   = lane >> 4;
  int rowB = rowblk*128;
  int rloc = wave*16 + lr;

  for (int rt=0; rt<8; rt++){
    int row0 = rowB + rt*16;
    const short* aRow = Hb + (size_t)(row0 + lr)*256 + qg*8;
    f32x4 acc = (f32x4){0.f,0.f,0.f,0.f};
    #pragma unroll
    for (int ks=0; ks<8; ks++){
      short8v a = *(const short8v*)(aRow + ks*32);
      int e = rloc*256 + ks*32 + qg*8;
      short8v b = *(const short8v*)(ldsW + WSWZ(e, rloc));
      acc = __builtin_amdgcn_mfma_f32_16x16x32_bf16(a, b, acc, 0, 0, 0);
    }
    int mrow = row0 + qg*4;
    int cout = half*128 + wave*16 + lr;
    #pragma unroll
    for (int r=0;r<4;r++)
      Ab[(size_t)(mrow + r)*256 + cout] = f2bf(acc[r]);
  }
}

// ---------------- aggregation: 32 lanes/node, XCD-swizzled, bf16 out --------
__global__ __launch_bounds__(256) void k_agg(const short* __restrict__ Ab,
    const int* __restrict__ rowptr, const int* __restrict__ col,
    const float* __restrict__ dinv, const float* __restrict__ bvec,
    unsigned* __restrict__ outU, float* __restrict__ partS, float* __restrict__ partQ){
  int bid  = (int)(blockIdx.x & 7) * 512 + (int)(blockIdx.x >> 3);  // XCD swizzle
  int node = bid*8 + (threadIdx.x >> 5);
  int sub  = threadIdx.x & 31;
  int c0   = sub*8;
  float dv = dinv[node];

  float acc[8];
  {
    short8v s = *(const short8v*)&Ab[(size_t)node*256 + c0];
    #pragma unroll
    for (int i=0;i<8;i++) acc[i] = dv * bf2f(s[i]);
  }
  int j0 = rowptr[node], j1 = rowptr[node+1];
  for (int j=j0;j<j1;j++){
    int s = col[j];
    float ds = dinv[s];
    short8v nb = *(const short8v*)&Ab[(size_t)s*256 + c0];
    #pragma unroll
    for (int i=0;i<8;i++) acc[i] += ds * bf2f(nb[i]);
  }
  float sum=0.f, sq=0.f;
  float o[8];
  #pragma unroll
  for (int i=0;i<8;i++){
    float v = dv*acc[i] + bvec[c0+i];
    o[i] = v;
    sum += v; sq += v*v;
  }
  uint4 ov;
  ov.x = pkbf(o[0],o[1]); ov.y = pkbf(o[2],o[3]);
  ov.z = pkbf(o[4],o[5]); ov.w = pkbf(o[6],o[7]);
  *(uint4*)&outU[(size_t)node*128 + sub*4] = ov;

  #pragma unroll
  for (int off=16; off>0; off>>=1){
    sum += __shfl_down(sum, off, 32);
    sq  += __shfl_down(sq,  off, 32);
  }
  __shared__ float ls1[8], ls2[8];
  if (sub==0){ ls1[threadIdx.x>>5]=sum; ls2[threadIdx.x>>5]=sq; }
  __syncthreads();
  if (threadIdx.x==0){
    float a=0.f, b=0.f;
    #pragma unroll
    for (int i=0;i<8;i++){ a+=ls1[i]; b+=ls2[i]; }
    partS[bid]=a; partQ[bid]=b;
  }
}

// ---------------- stats over 4096 per-block partials (double accum) ---------
__global__ void k_stats(const float* __restrict__ partS, const float* __restrict__ partQ,
                        float* __restrict__ stats){
  __shared__ double s1[1024], s2[1024];
  int t = threadIdx.x;
  double a=0.0, b=0.0;
  for (int i=t; i<4096; i+=1024){ a += (double)partS[i]; b += (double)partQ[i]; }
  s1[t]=a; s2[t]=b; __syncthreads();
  for (int off=512; off>0; off>>=1){
    if (t<off){ s1[t]+=s1[t+off]; s2[t]+=s2[t+off]; }
    __syncthreads();
  }
  if (t==0){
    double mean = s1[0] / (double)NP_;
    double var  = s2[0] / (double)NP_ - mean*mean;
    var = var > 0.0 ? var : 0.0;
    stats[0] = (float)mean;
    stats[1] = (float)(1.0 / (sqrt(var) + (double)EPS_));
  }
}

// ---------------- norm + prelu (bf16 in; bf16 or f32 out), 8 elems/thread ---
__device__ __forceinline__ void unpack2(unsigned u, float& lo, float& hi){
  lo = __uint_as_float(u << 16);
  hi = __uint_as_float(u & 0xFFFF0000u);
}

__global__ __launch_bounds__(256) void k_norm_bf16(const unsigned* __restrict__ inU,
    const float* __restrict__ g, const float* __restrict__ be,
    const float* __restrict__ aP, const float* __restrict__ stats,
    unsigned* __restrict__ outU){
  float mean = stats[0], inv = stats[1], a = aP[0];
  int gid   = blockIdx.x*256 + threadIdx.x;
  int base8 = gid*8;
  int c0    = base8 & (D_-1);
  uint4 vin = *(const uint4*)&inU[gid*4];
  float4 g0 = *(const float4*)&g[c0],  g1 = *(const float4*)&g[c0+4];
  float4 e0 = *(const float4*)&be[c0], e1 = *(const float4*)&be[c0+4];
  float v[8];
  unpack2(vin.x, v[0], v[1]); unpack2(vin.y, v[2], v[3]);
  unpack2(vin.z, v[4], v[5]); unpack2(vin.w, v[6], v[7]);
  float gg[8] = {g0.x,g0.y,g0.z,g0.w,g1.x,g1.y,g1.z,g1.w};
  float eb[8] = {e0.x,e0.y,e0.z,e0.w,e1.x,e1.y,e1.z,e1.w};
  float o[8];
  #pragma unroll
  for (int i=0;i<8;i++){
    float t = gg[i]*((v[i]-mean)*inv) + eb[i];
    o[i] = t>=0.f ? t : a*t;
  }
  uint4 ov;
  ov.x = pkbf(o[0],o[1]); ov.y = pkbf(o[2],o[3]);
  ov.z = pkbf(o[4],o[5]); ov.w = pkbf(o[6],o[7]);
  *(uint4*)&outU[gid*4] = ov;
}

__global__ __launch_bounds__(256) void k_norm_f32(const unsigned* __restrict__ inU,
    const float* __restrict__ g, const float* __restrict__ be,
    const float* __restrict__ aP, const float* __restrict__ stats,
    float* __restrict__ out){
  float mean = stats[0], inv = stats[1], a = aP[0];
  int gid   = blockIdx.x*256 + threadIdx.x;
  int base8 = gid*8;
  int c0    = base8 & (D_-1);
  uint4 vin = *(const uint4*)&inU[gid*4];
  float4 g0 = *(const float4*)&g[c0],  g1 = *(const float4*)&g[c0+4];
  float4 e0 = *(const float4*)&be[c0], e1 = *(const float4*)&be[c0+4];
  float v[8];
  unpack2(vin.x, v[0], v[1]); unpack2(vin.y, v[2], v[3]);
  unpack2(vin.z, v[4], v[5]); unpack2(vin.w, v[6], v[7]);
  float gg[8] = {g0.x,g0.y,g0.z,g0.w,g1.x,g1.y,g1.z,g1.w};
  float eb[8] = {e0.x,e0.y,e0.z,e0.w,e1.x,e1.y,e1.z,e1.w};
  f32x4 o0, o1;
  #pragma unroll
  for (int i=0;i<8;i++){
    float t = gg[i]*((v[i]-mean)*inv) + eb[i];
    t = t>=0.f ? t : a*t;
    if (i<4) o0[i] = t; else o1[i-4] = t;
  }
  *(f32x4*)&out[base8]     = o0;
  *(f32x4*)&out[base8 + 4] = o1;
}

// ---------------- launch ----------------

extern "C" void kernel_launch(void* const* d_in, const int* in_sizes, int n_in,
                              void* d_out, int out_size, void* d_ws, size_t ws_size,
                              hipStream_t stream){
  const float* x    = (const float*)d_in[0];
  const int*   knn  = (const int*)  d_in[1];
  const void*  mask =               d_in[2];
  const float* W0   = (const float*)d_in[3];
  const float* b0   = (const float*)d_in[4];
  const float* g0   = (const float*)d_in[5];
  const float* be0  = (const float*)d_in[6];
  const float* a0   = (const float*)d_in[7];
  const float* W1   = (const float*)d_in[8];
  const float* b1   = (const float*)d_in[9];
  const float* g1   = (const float*)d_in[10];
  const float* be1  = (const float*)d_in[11];
  const float* a1   = (const float*)d_in[12];
  float* out = (float*)d_out;

  char* w = (char*)d_ws;
  size_t off = 0;
  auto alloc = [&](size_t bytes)->void*{
    void* p = w + off; off = (off + bytes + 255) & ~(size_t)255; return p;
  };
  int*      degcnt  = (int*)     alloc(NT_*4);
  int*      rowptr  = (int*)     alloc((NT_+1)*4);
  int*      fillptr = (int*)     alloc(NT_*4);
  int*      col     = (int*)     alloc(E16_*4);
  float*    dinv    = (float*)   alloc(NT_*4);
  float*    partS   = (float*)   alloc(4096*4);
  float*    partQ   = (float*)   alloc(4096*4);
  float*    stats   = (float*)   alloc(4*4);
  int*      flag    = (int*)     alloc(4);
  short*    Hb      = (short*)   alloc((size_t)NP_*2);   // layer-1 input (bf16)
  short*    Ab      = (short*)   alloc((size_t)NP_*2);   // gemm output (bf16)
  unsigned* Bagg    = (unsigned*)alloc((size_t)NP_*2);   // agg output (bf16 pairs)
  short*    Wt0     = (short*)   alloc(256*256*2);
  short*    Wt1     = (short*)   alloc(256*256*2);

  // edge structure + weights
  hipLaunchKernelGGL(k_init,  dim3(NT_/256),  dim3(256), 0, stream, degcnt, (const unsigned int*)mask, flag);
  hipLaunchKernelGGL(k_deg,   dim3(E16_/256), dim3(256), 0, stream, knn, mask, flag, degcnt);
  hipLaunchKernelGGL(k_scan,  dim3(1),        dim3(1024),0, stream, degcnt, rowptr, fillptr, dinv);
  hipLaunchKernelGGL(k_fill,  dim3(E16_/256), dim3(256), 0, stream, knn, mask, flag, fillptr, col);
  hipLaunchKernelGGL(k_cvt_w, dim3(128),      dim3(256), 0, stream, W0, W1, Wt0, Wt1);

  // layer 0
  hipLaunchKernelGGL(k_gemm_x, dim3(512),     dim3(512), 0, stream, x, Wt0, Ab);
  hipLaunchKernelGGL(k_agg,    dim3(NT_/8),   dim3(256), 0, stream, Ab, rowptr, col, dinv, b0, Bagg, partS, partQ);
  hipLaunchKernelGGL(k_stats,  dim3(1),       dim3(1024),0, stream, partS, partQ, stats);
  hipLaunchKernelGGL(k_norm_bf16, dim3(NP_/2048), dim3(256), 0, stream, Bagg, g0, be0, a0, stats, (unsigned*)Hb);

  // layer 1
  hipLaunchKernelGGL(k_gemm_h, dim3(512),     dim3(512), 0, stream, Hb, Wt1, Ab);
  hipLaunchKernelGGL(k_agg,    dim3(NT_/8),   dim3(256), 0, stream, Ab, rowptr, col, dinv, b1, Bagg, partS, partQ);
  hipLaunchKernelGGL(k_stats,  dim3(1),       dim3(1024),0, stream, partS, partQ, stats);
  hipLaunchKernelGGL(k_norm_f32,  dim3(NP_/2048), dim3(256), 0, stream, Bagg, g1, be1, a1, stats, out);
}

// Round 9
// 202.653 us; speedup vs baseline: 1.1916x; 1.1916x over previous
//
#include <hip/hip_runtime.h>
#include <hip/hip_bf16.h>
#include <stdint.h>

#define B_   8
#define N_   4096
#define K1_  17
#define D_   256
#define NT_  (B_*N_)          // 32768
#define E16_ (NT_*16)         // 524288
#define NP_  (NT_*D_)         // 8388608
#define EPS_ 1e-5f

typedef __attribute__((ext_vector_type(8))) short short8v;  // 8 bf16 (4 VGPR)
typedef __attribute__((ext_vector_type(4))) short short4v;
typedef __attribute__((ext_vector_type(4))) float f32x4;

// f32 -> bf16 RNE, pure C
__device__ __forceinline__ unsigned short f2bfu(float f){
  unsigned u = __float_as_uint(f);
  unsigned r = (u + 0x7FFFu + ((u>>16)&1u)) >> 16;
  return (unsigned short)r;
}
__device__ __forceinline__ short f2bf(float f){ return (short)f2bfu(f); }
__device__ __forceinline__ unsigned pkbf(float lo, float hi){
  return (unsigned)f2bfu(lo) | ((unsigned)f2bfu(hi) << 16);
}
__device__ __forceinline__ float bf2f(short s){
  return __uint_as_float(((unsigned)(unsigned short)s) << 16);
}

// ---------------- edge-structure kernels ----------------

__global__ __launch_bounds__(256) void k_init(int* __restrict__ degcnt,
                                              const unsigned int* __restrict__ mw,
                                              int* __restrict__ flag){
  int i = blockIdx.x*256 + threadIdx.x;
  degcnt[i] = 0;
  if (blockIdx.x == 0){
    __shared__ int s_int, s_f32;
    if (threadIdx.x==0){ s_int=1; s_f32=1; }
    __syncthreads();
    int bad_i=0, bad_f=0;
    #pragma unroll
    for (int j=0;j<4;j++){
      unsigned w = mw[threadIdx.x*4 + j];
      if (!(w==0u || w==1u))          bad_i=1;
      if (!(w==0u || w==0x3F800000u)) bad_f=1;
    }
    if (bad_i) atomicAnd(&s_int, 0);
    if (bad_f) atomicAnd(&s_f32, 0);
    __syncthreads();
    if (threadIdx.x==0) *flag = s_int ? 0 : (s_f32 ? 1 : 2);
  }
}

__device__ __forceinline__ bool mask_at(const void* maskp, int f, int idx){
  if (f==0) return ((const int*)maskp)[idx] != 0;
  if (f==1) return ((const float*)maskp)[idx] != 0.0f;
  return ((const unsigned char*)maskp)[idx] != 0;
}

__global__ void k_deg(const int* __restrict__ knn, const void* __restrict__ maskp,
                      const int* __restrict__ flag, int* __restrict__ degcnt){
  int f = *flag;
  int e = blockIdx.x*blockDim.x + threadIdx.x;
  if (e >= E16_) return;
  int node = e >> 4;
  int k    = (e & 15) + 1;
  int idx  = node*K1_ + k;
  if (mask_at(maskp, f, idx)){
    int b   = node >> 12;
    int dst = knn[idx] + (b<<12);
    atomicAdd(&degcnt[dst], 1);
  }
}

__global__ void k_scan(const int* __restrict__ degcnt, int* __restrict__ rowptr,
                       int* __restrict__ fillptr, float* __restrict__ dinv){
  __shared__ int sm[1024];
  int t = threadIdx.x;
  int base = t*32;
  int loc[32]; int tot = 0;
  #pragma unroll
  for (int i=0;i<32;i++){ loc[i] = degcnt[base+i]; tot += loc[i]; }
  sm[t] = tot; __syncthreads();
  for (int off=1; off<1024; off<<=1){
    int v = (t>=off) ? sm[t-off] : 0;
    __syncthreads();
    sm[t] += v;
    __syncthreads();
  }
  int run = sm[t] - tot;
  #pragma unroll
  for (int i=0;i<32;i++){
    int v = base+i;
    rowptr[v]  = run;
    fillptr[v] = run;
    dinv[v]    = rsqrtf((float)loc[i] + 1.0f);
    run += loc[i];
  }
  if (t==1023) rowptr[NT_] = run;
}

__global__ void k_fill(const int* __restrict__ knn, const void* __restrict__ maskp,
                       const int* __restrict__ flag, int* __restrict__ fillptr,
                       int* __restrict__ col){
  int f = *flag;
  int e = blockIdx.x*blockDim.x + threadIdx.x;
  if (e >= E16_) return;
  int node = e >> 4;
  int k    = (e & 15) + 1;
  int idx  = node*K1_ + k;
  if (mask_at(maskp, f, idx)){
    int b   = node >> 12;
    int dst = knn[idx] + (b<<12);
    int pos = atomicAdd(&fillptr[dst], 1);
    col[pos] = node;
  }
}

// ---------------- conversions ----------------

// x[:,0,:] (f32, row stride 512) -> Hb0 bf16 [NT][256], coalesced
__global__ __launch_bounds__(256) void k_cvt_x(const float* __restrict__ x,
                                               short* __restrict__ Hb0){
  int gid = blockIdx.x*256 + threadIdx.x;
  int row = gid >> 6;
  int col = (gid & 63) * 4;
  float4 v = *(const float4*)&x[(size_t)row*512 + col];
  short4v o = { f2bf(v.x), f2bf(v.y), f2bf(v.z), f2bf(v.w) };
  *(short4v*)&Hb0[(size_t)row*256 + col] = o;
}

// Wt[n][k] = bf16(W[k][n]), plain layout, LDS-tiled transpose
__global__ __launch_bounds__(256) void k_cvt_w(const float* __restrict__ W0,
                                               const float* __restrict__ W1,
                                               short* __restrict__ Wt0,
                                               short* __restrict__ Wt1){
  const float* W  = (blockIdx.x & 1) ? W1  : W0;
  short*       Wt = (blockIdx.x & 1) ? Wt1 : Wt0;
  int tile = blockIdx.x >> 1;
  int ti = tile >> 3, tj = tile & 7;
  __shared__ float sm[32][33];
  int r = threadIdx.x >> 5, c = threadIdx.x & 31;
  #pragma unroll
  for (int i=0;i<4;i++)
    sm[r + i*8][c] = W[(ti*32 + r + i*8)*256 + tj*32 + c];
  __syncthreads();
  #pragma unroll
  for (int i=0;i<4;i++){
    int rr = r + i*8;
    Wt[(size_t)(tj*32 + rr)*256 + ti*32 + c] = f2bf(sm[c][rr]);
  }
}

// ---------------- MFMA GEMM, m97 structure: A and B staged in LDS ----------
// 256 thr = 4 waves (2x2). Tile 128 rows x 128 cols, BK=64, 4 K-steps.
// Staging: 8 consecutive threads read one row's contiguous 128B (full-granule
// coalescing -- fixes the 16-row scatter that TA-bound all prior variants).
// LDS chunk swizzle: chunk' = chunk ^ (row&7) on BOTH ds_write and ds_read
// (same kernel, rule-21 safe) -> 2-way bank aliasing only (free, m136).
// Prefetch (T14-lite): issue kc+1 global loads between barrier and compute.
// Frag maps (validated rounds 1-8):
//  A: lane l holds row m*16+(l&15), k = ks*32 + 8*(l>>4)+j
//  B: lane l holds col n*16+(l&15), same k
//  D: lane l reg r -> C[m*16 + 4*(l>>4)+r][n*16 + (l&15)]
__global__ __launch_bounds__(256, 3) void k_gemm(const short* __restrict__ Ag,
                                                 const short* __restrict__ Wt,
                                                 short* __restrict__ C){
  __shared__ short lA[128*64];   // 16KB
  __shared__ short lB[128*64];   // 16KB
  int lb     = (int)(blockIdx.x & 7)*64 + (int)(blockIdx.x >> 3);  // XCD chunk
  int rowblk = lb >> 1, half = lb & 1;
  int rowB = rowblk*128, colB = half*128;

  int t    = threadIdx.x;
  int wave = t >> 6, lane = t & 63;
  int lr   = lane & 15, qg = lane >> 4;
  int wr   = wave >> 1, wc = wave & 1;

  f32x4 acc[4][4];
  #pragma unroll
  for (int m=0;m<4;m++)
    #pragma unroll
    for (int n=0;n<4;n++) acc[m][n] = (f32x4){0.f,0.f,0.f,0.f};

  int srow[4], sch[4];
  #pragma unroll
  for (int i=0;i<4;i++){ int e = t + i*256; srow[i] = e>>3; sch[i] = e&7; }

  uint4 ra[4], rb[4];
  #pragma unroll
  for (int i=0;i<4;i++){
    ra[i] = *(const uint4*)(Ag + (size_t)(rowB+srow[i])*256 + sch[i]*8);
    rb[i] = *(const uint4*)(Wt + (size_t)(colB+srow[i])*256 + sch[i]*8);
  }

  for (int kc=0; kc<4; kc++){
    if (kc) __syncthreads();              // previous compute done
    #pragma unroll
    for (int i=0;i<4;i++){
      int ph = srow[i]*8 + (sch[i] ^ (srow[i]&7));
      *(uint4*)(lA + ph*8) = ra[i];
      *(uint4*)(lB + ph*8) = rb[i];
    }
    __syncthreads();
    if (kc < 3){                          // prefetch next K-step (hidden under MFMA)
      #pragma unroll
      for (int i=0;i<4;i++){
        ra[i] = *(const uint4*)(Ag + (size_t)(rowB+srow[i])*256 + (kc+1)*64 + sch[i]*8);
        rb[i] = *(const uint4*)(Wt + (size_t)(colB+srow[i])*256 + (kc+1)*64 + sch[i]*8);
      }
    }
    #pragma unroll
    for (int ks=0; ks<2; ks++){
      short8v af[4], bf[4];
      #pragma unroll
      for (int m=0;m<4;m++){
        int row = wr*64 + m*16 + lr;
        af[m] = *(const short8v*)(lA + (row*8 + ((ks*4+qg) ^ (row&7)))*8);
      }
      #pragma unroll
      for (int n=0;n<4;n++){
        int coln = wc*64 + n*16 + lr;
        bf[n] = *(const short8v*)(lB + (coln*8 + ((ks*4+qg) ^ (coln&7)))*8);
      }
      #pragma unroll
      for (int m=0;m<4;m++)
        #pragma unroll
        for (int n=0;n<4;n++)
          acc[m][n] = __builtin_amdgcn_mfma_f32_16x16x32_bf16(af[m], bf[n], acc[m][n], 0, 0, 0);
    }
  }

  #pragma unroll
  for (int m=0;m<4;m++){
    int crow = rowB + wr*64 + m*16 + qg*4;
    #pragma unroll
    for (int n=0;n<4;n++){
      int ccol = colB + wc*64 + n*16 + lr;
      #pragma unroll
      for (int r=0;r<4;r++)
        C[(size_t)(crow + r)*256 + ccol] = f2bf(acc[m][n][r]);
    }
  }
}

// ---------------- aggregation: 32 lanes/node, XCD-swizzled, bf16 out --------
__global__ __launch_bounds__(256) void k_agg(const short* __restrict__ Ab,
    const int* __restrict__ rowptr, const int* __restrict__ col,
    const float* __restrict__ dinv, const float* __restrict__ bvec,
    unsigned* __restrict__ outU, float* __restrict__ partS, float* __restrict__ partQ){
  int bid  = (int)(blockIdx.x & 7) * 512 + (int)(blockIdx.x >> 3);  // XCD swizzle
  int node = bid*8 + (threadIdx.x >> 5);
  int sub  = threadIdx.x & 31;
  int c0   = sub*8;
  float dv = dinv[node];

  float acc[8];
  {
    short8v s = *(const short8v*)&Ab[(size_t)node*256 + c0];
    #pragma unroll
    for (int i=0;i<8;i++) acc[i] = dv * bf2f(s[i]);
  }
  int j0 = rowptr[node], j1 = rowptr[node+1];
  for (int j=j0;j<j1;j++){
    int s = col[j];
    float ds = dinv[s];
    short8v nb = *(const short8v*)&Ab[(size_t)s*256 + c0];
    #pragma unroll
    for (int i=0;i<8;i++) acc[i] += ds * bf2f(nb[i]);
  }
  float sum=0.f, sq=0.f;
  float o[8];
  #pragma unroll
  for (int i=0;i<8;i++){
    float v = dv*acc[i] + bvec[c0+i];
    o[i] = v;
    sum += v; sq += v*v;
  }
  uint4 ov;
  ov.x = pkbf(o[0],o[1]); ov.y = pkbf(o[2],o[3]);
  ov.z = pkbf(o[4],o[5]); ov.w = pkbf(o[6],o[7]);
  *(uint4*)&outU[(size_t)node*128 + sub*4] = ov;

  #pragma unroll
  for (int off=16; off>0; off>>=1){
    sum += __shfl_down(sum, off, 32);
    sq  += __shfl_down(sq,  off, 32);
  }
  __shared__ float ls1[8], ls2[8];
  if (sub==0){ ls1[threadIdx.x>>5]=sum; ls2[threadIdx.x>>5]=sq; }
  __syncthreads();
  if (threadIdx.x==0){
    float a=0.f, b=0.f;
    #pragma unroll
    for (int i=0;i<8;i++){ a+=ls1[i]; b+=ls2[i]; }
    partS[bid]=a; partQ[bid]=b;
  }
}

// ---------------- stats over 4096 per-block partials (double accum) ---------
__global__ void k_stats(const float* __restrict__ partS, const float* __restrict__ partQ,
                        float* __restrict__ stats){
  __shared__ double s1[1024], s2[1024];
  int t = threadIdx.x;
  double a=0.0, b=0.0;
  for (int i=t; i<4096; i+=1024){ a += (double)partS[i]; b += (double)partQ[i]; }
  s1[t]=a; s2[t]=b; __syncthreads();
  for (int off=512; off>0; off>>=1){
    if (t<off){ s1[t]+=s1[t+off]; s2[t]+=s2[t+off]; }
    __syncthreads();
  }
  if (t==0){
    double mean = s1[0] / (double)NP_;
    double var  = s2[0] / (double)NP_ - mean*mean;
    var = var > 0.0 ? var : 0.0;
    stats[0] = (float)mean;
    stats[1] = (float)(1.0 / (sqrt(var) + (double)EPS_));
  }
}

// ---------------- norm + prelu (bf16 in; bf16 or f32 out), 8 elems/thread ---
__device__ __forceinline__ void unpack2(unsigned u, float& lo, float& hi){
  lo = __uint_as_float(u << 16);
  hi = __uint_as_float(u & 0xFFFF0000u);
}

__global__ __launch_bounds__(256) void k_norm_bf16(const unsigned* __restrict__ inU,
    const float* __restrict__ g, const float* __restrict__ be,
    const float* __restrict__ aP, const float* __restrict__ stats,
    unsigned* __restrict__ outU){
  float mean = stats[0], inv = stats[1], a = aP[0];
  int gid   = blockIdx.x*256 + threadIdx.x;
  int base8 = gid*8;
  int c0    = base8 & (D_-1);
  uint4 vin = *(const uint4*)&inU[gid*4];
  float4 g0 = *(const float4*)&g[c0],  g1 = *(const float4*)&g[c0+4];
  float4 e0 = *(const float4*)&be[c0], e1 = *(const float4*)&be[c0+4];
  float v[8];
  unpack2(vin.x, v[0], v[1]); unpack2(vin.y, v[2], v[3]);
  unpack2(vin.z, v[4], v[5]); unpack2(vin.w, v[6], v[7]);
  float gg[8] = {g0.x,g0.y,g0.z,g0.w,g1.x,g1.y,g1.z,g1.w};
  float eb[8] = {e0.x,e0.y,e0.z,e0.w,e1.x,e1.y,e1.z,e1.w};
  float o[8];
  #pragma unroll
  for (int i=0;i<8;i++){
    float tt = gg[i]*((v[i]-mean)*inv) + eb[i];
    o[i] = tt>=0.f ? tt : a*tt;
  }
  uint4 ov;
  ov.x = pkbf(o[0],o[1]); ov.y = pkbf(o[2],o[3]);
  ov.z = pkbf(o[4],o[5]); ov.w = pkbf(o[6],o[7]);
  *(uint4*)&outU[gid*4] = ov;
}

__global__ __launch_bounds__(256) void k_norm_f32(const unsigned* __restrict__ inU,
    const float* __restrict__ g, const float* __restrict__ be,
    const float* __restrict__ aP, const float* __restrict__ stats,
    float* __restrict__ out){
  float mean = stats[0], inv = stats[1], a = aP[0];
  int gid   = blockIdx.x*256 + threadIdx.x;
  int base8 = gid*8;
  int c0    = base8 & (D_-1);
  uint4 vin = *(const uint4*)&inU[gid*4];
  float4 g0 = *(const float4*)&g[c0],  g1 = *(const float4*)&g[c0+4];
  float4 e0 = *(const float4*)&be[c0], e1 = *(const float4*)&be[c0+4];
  float v[8];
  unpack2(vin.x, v[0], v[1]); unpack2(vin.y, v[2], v[3]);
  unpack2(vin.z, v[4], v[5]); unpack2(vin.w, v[6], v[7]);
  float gg[8] = {g0.x,g0.y,g0.z,g0.w,g1.x,g1.y,g1.z,g1.w};
  float eb[8] = {e0.x,e0.y,e0.z,e0.w,e1.x,e1.y,e1.z,e1.w};
  f32x4 o0, o1;
  #pragma unroll
  for (int i=0;i<8;i++){
    float tt = gg[i]*((v[i]-mean)*inv) + eb[i];
    tt = tt>=0.f ? tt : a*tt;
    if (i<4) o0[i] = tt; else o1[i-4] = tt;
  }
  *(f32x4*)&out[base8]     = o0;
  *(f32x4*)&out[base8 + 4] = o1;
}

// ---------------- launch ----------------

extern "C" void kernel_launch(void* const* d_in, const int* in_sizes, int n_in,
                              void* d_out, int out_size, void* d_ws, size_t ws_size,
                              hipStream_t stream){
  const float* x    = (const float*)d_in[0];
  const int*   knn  = (const int*)  d_in[1];
  const void*  mask =               d_in[2];
  const float* W0   = (const float*)d_in[3];
  const float* b0   = (const float*)d_in[4];
  const float* g0   = (const float*)d_in[5];
  const float* be0  = (const float*)d_in[6];
  const float* a0   = (const float*)d_in[7];
  const float* W1   = (const float*)d_in[8];
  const float* b1   = (const float*)d_in[9];
  const float* g1   = (const float*)d_in[10];
  const float* be1  = (const float*)d_in[11];
  const float* a1   = (const float*)d_in[12];
  float* out = (float*)d_out;

  char* w = (char*)d_ws;
  size_t off = 0;
  auto alloc = [&](size_t bytes)->void*{
    void* p = w + off; off = (off + bytes + 255) & ~(size_t)255; return p;
  };
  int*      degcnt  = (int*)     alloc(NT_*4);
  int*      rowptr  = (int*)     alloc((NT_+1)*4);
  int*      fillptr = (int*)     alloc(NT_*4);
  int*      col     = (int*)     alloc(E16_*4);
  float*    dinv    = (float*)   alloc(NT_*4);
  float*    partS   = (float*)   alloc(4096*4);
  float*    partQ   = (float*)   alloc(4096*4);
  float*    stats   = (float*)   alloc(4*4);
  int*      flag    = (int*)     alloc(4);
  short*    Hb0     = (short*)   alloc((size_t)NP_*2);   // layer-0 input (bf16 of x)
  short*    Hb      = (short*)   alloc((size_t)NP_*2);   // layer-1 input (bf16)
  short*    Ab      = (short*)   alloc((size_t)NP_*2);   // gemm output (bf16)
  unsigned* Bagg    = (unsigned*)alloc((size_t)NP_*2);   // agg output (bf16 pairs)
  short*    Wt0     = (short*)   alloc(256*256*2);
  short*    Wt1     = (short*)   alloc(256*256*2);

  // edge structure + conversions
  hipLaunchKernelGGL(k_init,  dim3(NT_/256),  dim3(256), 0, stream, degcnt, (const unsigned int*)mask, flag);
  hipLaunchKernelGGL(k_deg,   dim3(E16_/256), dim3(256), 0, stream, knn, mask, flag, degcnt);
  hipLaunchKernelGGL(k_scan,  dim3(1),        dim3(1024),0, stream, degcnt, rowptr, fillptr, dinv);
  hipLaunchKernelGGL(k_fill,  dim3(E16_/256), dim3(256), 0, stream, knn, mask, flag, fillptr, col);
  hipLaunchKernelGGL(k_cvt_w, dim3(128),      dim3(256), 0, stream, W0, W1, Wt0, Wt1);
  hipLaunchKernelGGL(k_cvt_x, dim3(NT_/4),    dim3(256), 0, stream, x, Hb0);

  // layer 0
  hipLaunchKernelGGL(k_gemm,  dim3(512),      dim3(256), 0, stream, Hb0, Wt0, Ab);
  hipLaunchKernelGGL(k_agg,   dim3(NT_/8),    dim3(256), 0, stream, Ab, rowptr, col, dinv, b0, Bagg, partS, partQ);
  hipLaunchKernelGGL(k_stats, dim3(1),        dim3(1024),0, stream, partS, partQ, stats);
  hipLaunchKernelGGL(k_norm_bf16, dim3(NP_/2048), dim3(256), 0, stream, Bagg, g0, be0, a0, stats, (unsigned*)Hb);

  // layer 1
  hipLaunchKernelGGL(k_gemm,  dim3(512),      dim3(256), 0, stream, Hb, Wt1, Ab);
  hipLaunchKernelGGL(k_agg,   dim3(NT_/8),    dim3(256), 0, stream, Ab, rowptr, col, dinv, b1, Bagg, partS, partQ);
  hipLaunchKernelGGL(k_stats, dim3(1),        dim3(1024),0, stream, partS, partQ, stats);
  hipLaunchKernelGGL(k_norm_f32,  dim3(NP_/2048), dim3(256), 0, stream, Bagg, g1, be1, a1, stats, out);
}

// Round 10
// 176.517 us; speedup vs baseline: 1.3681x; 1.1481x over previous
//
#include <hip/hip_runtime.h>
#include <hip/hip_bf16.h>
#include <stdint.h>

#define B_   8
#define N_   4096
#define K1_  17
#define D_   256
#define NT_  (B_*N_)          // 32768
#define E16_ (NT_*16)         // 524288
#define NP_  (NT_*D_)         // 8388608
#define EPS_ 1e-5f

typedef __attribute__((ext_vector_type(8))) short short8v;  // 8 bf16 (4 VGPR)
typedef __attribute__((ext_vector_type(4))) short short4v;
typedef __attribute__((ext_vector_type(4))) float f32x4;

// f32 -> bf16 RNE, pure C
__device__ __forceinline__ unsigned short f2bfu(float f){
  unsigned u = __float_as_uint(f);
  unsigned r = (u + 0x7FFFu + ((u>>16)&1u)) >> 16;
  return (unsigned short)r;
}
__device__ __forceinline__ short f2bf(float f){ return (short)f2bfu(f); }
__device__ __forceinline__ unsigned pkbf(float lo, float hi){
  return (unsigned)f2bfu(lo) | ((unsigned)f2bfu(hi) << 16);
}
__device__ __forceinline__ float bf2f(short s){
  return __uint_as_float(((unsigned)(unsigned short)s) << 16);
}
__device__ __forceinline__ void unpack2(unsigned u, float& lo, float& hi){
  lo = __uint_as_float(u << 16);
  hi = __uint_as_float(u & 0xFFFF0000u);
}

// ---------------- edge-structure kernels ----------------

__global__ __launch_bounds__(256) void k_init(int* __restrict__ degcnt,
                                              const unsigned int* __restrict__ mw,
                                              int* __restrict__ flag){
  int i = blockIdx.x*256 + threadIdx.x;
  degcnt[i] = 0;
  if (blockIdx.x == 0){
    __shared__ int s_int, s_f32;
    if (threadIdx.x==0){ s_int=1; s_f32=1; }
    __syncthreads();
    int bad_i=0, bad_f=0;
    #pragma unroll
    for (int j=0;j<4;j++){
      unsigned w = mw[threadIdx.x*4 + j];
      if (!(w==0u || w==1u))          bad_i=1;
      if (!(w==0u || w==0x3F800000u)) bad_f=1;
    }
    if (bad_i) atomicAnd(&s_int, 0);
    if (bad_f) atomicAnd(&s_f32, 0);
    __syncthreads();
    if (threadIdx.x==0) *flag = s_int ? 0 : (s_f32 ? 1 : 2);
  }
}

__device__ __forceinline__ bool mask_at(const void* maskp, int f, int idx){
  if (f==0) return ((const int*)maskp)[idx] != 0;
  if (f==1) return ((const float*)maskp)[idx] != 0.0f;
  return ((const unsigned char*)maskp)[idx] != 0;
}

__global__ void k_deg(const int* __restrict__ knn, const void* __restrict__ maskp,
                      const int* __restrict__ flag, int* __restrict__ degcnt){
  int f = *flag;
  int e = blockIdx.x*blockDim.x + threadIdx.x;
  if (e >= E16_) return;
  int node = e >> 4;
  int k    = (e & 15) + 1;
  int idx  = node*K1_ + k;
  if (mask_at(maskp, f, idx)){
    int b   = node >> 12;
    int dst = knn[idx] + (b<<12);
    atomicAdd(&degcnt[dst], 1);
  }
}

__global__ void k_scan(const int* __restrict__ degcnt, int* __restrict__ rowptr,
                       int* __restrict__ fillptr, float* __restrict__ dinv){
  __shared__ int sm[1024];
  int t = threadIdx.x;
  int base = t*32;
  int loc[32]; int tot = 0;
  #pragma unroll
  for (int i=0;i<32;i++){ loc[i] = degcnt[base+i]; tot += loc[i]; }
  sm[t] = tot; __syncthreads();
  for (int off=1; off<1024; off<<=1){
    int v = (t>=off) ? sm[t-off] : 0;
    __syncthreads();
    sm[t] += v;
    __syncthreads();
  }
  int run = sm[t] - tot;
  #pragma unroll
  for (int i=0;i<32;i++){
    int v = base+i;
    rowptr[v]  = run;
    fillptr[v] = run;
    dinv[v]    = rsqrtf((float)loc[i] + 1.0f);
    run += loc[i];
  }
  if (t==1023) rowptr[NT_] = run;
}

__global__ void k_fill(const int* __restrict__ knn, const void* __restrict__ maskp,
                       const int* __restrict__ flag, int* __restrict__ fillptr,
                       int* __restrict__ col){
  int f = *flag;
  int e = blockIdx.x*blockDim.x + threadIdx.x;
  if (e >= E16_) return;
  int node = e >> 4;
  int k    = (e & 15) + 1;
  int idx  = node*K1_ + k;
  if (mask_at(maskp, f, idx)){
    int b   = node >> 12;
    int dst = knn[idx] + (b<<12);
    int pos = atomicAdd(&fillptr[dst], 1);
    col[pos] = node;
  }
}

// ---------------- weight transpose (both layers, LDS-tiled) ----------------
__global__ __launch_bounds__(256) void k_cvt_w(const float* __restrict__ W0,
                                               const float* __restrict__ W1,
                                               short* __restrict__ Wt0,
                                               short* __restrict__ Wt1){
  const float* W  = (blockIdx.x & 1) ? W1  : W0;
  short*       Wt = (blockIdx.x & 1) ? Wt1 : Wt0;
  int tile = blockIdx.x >> 1;
  int ti = tile >> 3, tj = tile & 7;
  __shared__ float sm[32][33];
  int r = threadIdx.x >> 5, c = threadIdx.x & 31;
  #pragma unroll
  for (int i=0;i<4;i++)
    sm[r + i*8][c] = W[(ti*32 + r + i*8)*256 + tj*32 + c];
  __syncthreads();
  #pragma unroll
  for (int i=0;i<4;i++){
    int rr = r + i*8;
    Wt[(size_t)(tj*32 + rr)*256 + ti*32 + c] = f2bf(sm[c][rr]);
  }
}

// ---------------- MFMA GEMM (m97 structure), fused input transforms --------
// 256 thr = 4 waves (2x2). Tile 128x128, BK=64, 4 K-steps. A and B staged in
// LDS via coalesced 8-thread/row loads; chunk swizzle ^(row&7) on write+read.
// Prefetch next K-step between barrier and compute.
//  A: lane l holds row m*16+(l&15), k = ks*32 + 8*(l>>4)+j
//  B: lane l holds col n*16+(l&15), same k
//  D: lane l reg r -> C[m*16 + 4*(l>>4)+r][n*16 + (l&15)]

// layer 0: A staged from x (f32, row stride 512), bf16-converted in staging.
__global__ __launch_bounds__(256, 3) void k_gemm_x(const float* __restrict__ X,
                                                   const short* __restrict__ Wt,
                                                   short* __restrict__ C){
  __shared__ short lA[128*64];   // 16KB
  __shared__ short lB[128*64];   // 16KB
  int lb     = (int)(blockIdx.x & 7)*64 + (int)(blockIdx.x >> 3);  // XCD chunk
  int rowblk = lb >> 1, half = lb & 1;
  int rowB = rowblk*128, colB = half*128;

  int t    = threadIdx.x;
  int wave = t >> 6, lane = t & 63;
  int lr   = lane & 15, qg = lane >> 4;
  int wr   = wave >> 1, wc = wave & 1;

  f32x4 acc[4][4];
  #pragma unroll
  for (int m=0;m<4;m++)
    #pragma unroll
    for (int n=0;n<4;n++) acc[m][n] = (f32x4){0.f,0.f,0.f,0.f};

  int srow[4], sch[4];
  #pragma unroll
  for (int i=0;i<4;i++){ int e = t + i*256; srow[i] = e>>3; sch[i] = e&7; }

  float4 rax[4], ray[4]; uint4 rb[4];
  #pragma unroll
  for (int i=0;i<4;i++){
    const float* ap = X + (size_t)(rowB+srow[i])*512 + sch[i]*8;
    rax[i] = *(const float4*)ap;
    ray[i] = *(const float4*)(ap+4);
    rb[i]  = *(const uint4*)(Wt + (size_t)(colB+srow[i])*256 + sch[i]*8);
  }

  for (int kc=0; kc<4; kc++){
    if (kc) __syncthreads();
    #pragma unroll
    for (int i=0;i<4;i++){
      int ph = srow[i]*8 + (sch[i] ^ (srow[i]&7));
      uint4 cv;
      cv.x = pkbf(rax[i].x, rax[i].y); cv.y = pkbf(rax[i].z, rax[i].w);
      cv.z = pkbf(ray[i].x, ray[i].y); cv.w = pkbf(ray[i].z, ray[i].w);
      *(uint4*)(lA + ph*8) = cv;
      *(uint4*)(lB + ph*8) = rb[i];
    }
    __syncthreads();
    if (kc < 3){
      #pragma unroll
      for (int i=0;i<4;i++){
        const float* ap = X + (size_t)(rowB+srow[i])*512 + (kc+1)*64 + sch[i]*8;
        rax[i] = *(const float4*)ap;
        ray[i] = *(const float4*)(ap+4);
        rb[i]  = *(const uint4*)(Wt + (size_t)(colB+srow[i])*256 + (kc+1)*64 + sch[i]*8);
      }
    }
    #pragma unroll
    for (int ks=0; ks<2; ks++){
      short8v af[4], bfr[4];
      #pragma unroll
      for (int m=0;m<4;m++){
        int row = wr*64 + m*16 + lr;
        af[m] = *(const short8v*)(lA + (row*8 + ((ks*4+qg) ^ (row&7)))*8);
      }
      #pragma unroll
      for (int n=0;n<4;n++){
        int coln = wc*64 + n*16 + lr;
        bfr[n] = *(const short8v*)(lB + (coln*8 + ((ks*4+qg) ^ (coln&7)))*8);
      }
      #pragma unroll
      for (int m=0;m<4;m++)
        #pragma unroll
        for (int n=0;n<4;n++)
          acc[m][n] = __builtin_amdgcn_mfma_f32_16x16x32_bf16(af[m], bfr[n], acc[m][n], 0, 0, 0);
    }
  }

  #pragma unroll
  for (int m=0;m<4;m++){
    int crow = rowB + wr*64 + m*16 + qg*4;
    #pragma unroll
    for (int n=0;n<4;n++){
      int ccol = colB + wc*64 + n*16 + lr;
      #pragma unroll
      for (int r=0;r<4;r++)
        C[(size_t)(crow + r)*256 + ccol] = f2bf(acc[m][n][r]);
    }
  }
}

// layer 1: A staged from Bagg (bf16 pairs) with fused graph-norm + PReLU.
// Identical arithmetic to the standalone k_norm_bf16 (f32 math + RNE pack).
__global__ __launch_bounds__(256, 3) void k_gemm_n(const unsigned* __restrict__ BaggU,
                                                   const float* __restrict__ g,
                                                   const float* __restrict__ be,
                                                   const float* __restrict__ aP,
                                                   const float* __restrict__ stats,
                                                   const short* __restrict__ Wt,
                                                   short* __restrict__ C){
  float mean = stats[0], inv = stats[1], a = aP[0];
  __shared__ short lA[128*64];
  __shared__ short lB[128*64];
  int lb     = (int)(blockIdx.x & 7)*64 + (int)(blockIdx.x >> 3);
  int rowblk = lb >> 1, half = lb & 1;
  int rowB = rowblk*128, colB = half*128;

  int t    = threadIdx.x;
  int wave = t >> 6, lane = t & 63;
  int lr   = lane & 15, qg = lane >> 4;
  int wr   = wave >> 1, wc = wave & 1;

  f32x4 acc[4][4];
  #pragma unroll
  for (int m=0;m<4;m++)
    #pragma unroll
    for (int n=0;n<4;n++) acc[m][n] = (f32x4){0.f,0.f,0.f,0.f};

  int srow[4], sch[4];
  #pragma unroll
  for (int i=0;i<4;i++){ int e = t + i*256; srow[i] = e>>3; sch[i] = e&7; }

  uint4 ra[4], rb[4];
  #pragma unroll
  for (int i=0;i<4;i++){
    ra[i] = *(const uint4*)(BaggU + (size_t)(rowB+srow[i])*128 + sch[i]*4);
    rb[i] = *(const uint4*)(Wt + (size_t)(colB+srow[i])*256 + sch[i]*8);
  }

  for (int kc=0; kc<4; kc++){
    if (kc) __syncthreads();
    #pragma unroll
    for (int i=0;i<4;i++){
      int ph = srow[i]*8 + (sch[i] ^ (srow[i]&7));
      int c0 = kc*64 + sch[i]*8;
      float4 g0 = *(const float4*)&g[c0],  g1 = *(const float4*)&g[c0+4];
      float4 e0 = *(const float4*)&be[c0], e1 = *(const float4*)&be[c0+4];
      float v[8];
      unpack2(ra[i].x, v[0], v[1]); unpack2(ra[i].y, v[2], v[3]);
      unpack2(ra[i].z, v[4], v[5]); unpack2(ra[i].w, v[6], v[7]);
      float gg[8] = {g0.x,g0.y,g0.z,g0.w,g1.x,g1.y,g1.z,g1.w};
      float eb[8] = {e0.x,e0.y,e0.z,e0.w,e1.x,e1.y,e1.z,e1.w};
      float o[8];
      #pragma unroll
      for (int j=0;j<8;j++){
        float tt = gg[j]*((v[j]-mean)*inv) + eb[j];
        o[j] = tt>=0.f ? tt : a*tt;
      }
      uint4 cv;
      cv.x = pkbf(o[0],o[1]); cv.y = pkbf(o[2],o[3]);
      cv.z = pkbf(o[4],o[5]); cv.w = pkbf(o[6],o[7]);
      *(uint4*)(lA + ph*8) = cv;
      *(uint4*)(lB + ph*8) = rb[i];
    }
    __syncthreads();
    if (kc < 3){
      #pragma unroll
      for (int i=0;i<4;i++){
        ra[i] = *(const uint4*)(BaggU + (size_t)(rowB+srow[i])*128 + (kc+1)*32 + sch[i]*4);
        rb[i] = *(const uint4*)(Wt + (size_t)(colB+srow[i])*256 + (kc+1)*64 + sch[i]*8);
      }
    }
    #pragma unroll
    for (int ks=0; ks<2; ks++){
      short8v af[4], bfr[4];
      #pragma unroll
      for (int m=0;m<4;m++){
        int row = wr*64 + m*16 + lr;
        af[m] = *(const short8v*)(lA + (row*8 + ((ks*4+qg) ^ (row&7)))*8);
      }
      #pragma unroll
      for (int n=0;n<4;n++){
        int coln = wc*64 + n*16 + lr;
        bfr[n] = *(const short8v*)(lB + (coln*8 + ((ks*4+qg) ^ (coln&7)))*8);
      }
      #pragma unroll
      for (int m=0;m<4;m++)
        #pragma unroll
        for (int n=0;n<4;n++)
          acc[m][n] = __builtin_amdgcn_mfma_f32_16x16x32_bf16(af[m], bfr[n], acc[m][n], 0, 0, 0);
    }
  }

  #pragma unroll
  for (int m=0;m<4;m++){
    int crow = rowB + wr*64 + m*16 + qg*4;
    #pragma unroll
    for (int n=0;n<4;n++){
      int ccol = colB + wc*64 + n*16 + lr;
      #pragma unroll
      for (int r=0;r<4;r++)
        C[(size_t)(crow + r)*256 + ccol] = f2bf(acc[m][n][r]);
    }
  }
}

// ---------------- aggregation: 32 lanes/node, XCD-swizzled, bf16 out --------
__global__ __launch_bounds__(256) void k_agg(const short* __restrict__ Ab,
    const int* __restrict__ rowptr, const int* __restrict__ col,
    const float* __restrict__ dinv, const float* __restrict__ bvec,
    unsigned* __restrict__ outU, float* __restrict__ partS, float* __restrict__ partQ){
  int bid  = (int)(blockIdx.x & 7) * 512 + (int)(blockIdx.x >> 3);  // XCD swizzle
  int node = bid*8 + (threadIdx.x >> 5);
  int sub  = threadIdx.x & 31;
  int c0   = sub*8;
  float dv = dinv[node];

  float acc[8];
  {
    short8v s = *(const short8v*)&Ab[(size_t)node*256 + c0];
    #pragma unroll
    for (int i=0;i<8;i++) acc[i] = dv * bf2f(s[i]);
  }
  int j0 = rowptr[node], j1 = rowptr[node+1];
  for (int j=j0;j<j1;j++){
    int s = col[j];
    float ds = dinv[s];
    short8v nb = *(const short8v*)&Ab[(size_t)s*256 + c0];
    #pragma unroll
    for (int i=0;i<8;i++) acc[i] += ds * bf2f(nb[i]);
  }
  float sum=0.f, sq=0.f;
  float o[8];
  #pragma unroll
  for (int i=0;i<8;i++){
    float v = dv*acc[i] + bvec[c0+i];
    o[i] = v;
    sum += v; sq += v*v;
  }
  uint4 ov;
  ov.x = pkbf(o[0],o[1]); ov.y = pkbf(o[2],o[3]);
  ov.z = pkbf(o[4],o[5]); ov.w = pkbf(o[6],o[7]);
  *(uint4*)&outU[(size_t)node*128 + sub*4] = ov;

  #pragma unroll
  for (int off=16; off>0; off>>=1){
    sum += __shfl_down(sum, off, 32);
    sq  += __shfl_down(sq,  off, 32);
  }
  __shared__ float ls1[8], ls2[8];
  if (sub==0){ ls1[threadIdx.x>>5]=sum; ls2[threadIdx.x>>5]=sq; }
  __syncthreads();
  if (threadIdx.x==0){
    float a=0.f, b=0.f;
    #pragma unroll
    for (int i=0;i<8;i++){ a+=ls1[i]; b+=ls2[i]; }
    partS[bid]=a; partQ[bid]=b;
  }
}

// ---------------- stats over 4096 per-block partials (double accum) ---------
__global__ void k_stats(const float* __restrict__ partS, const float* __restrict__ partQ,
                        float* __restrict__ stats){
  __shared__ double s1[1024], s2[1024];
  int t = threadIdx.x;
  double a=0.0, b=0.0;
  for (int i=t; i<4096; i+=1024){ a += (double)partS[i]; b += (double)partQ[i]; }
  s1[t]=a; s2[t]=b; __syncthreads();
  for (int off=512; off>0; off>>=1){
    if (t<off){ s1[t]+=s1[t+off]; s2[t]+=s2[t+off]; }
    __syncthreads();
  }
  if (t==0){
    double mean = s1[0] / (double)NP_;
    double var  = s2[0] / (double)NP_ - mean*mean;
    var = var > 0.0 ? var : 0.0;
    stats[0] = (float)mean;
    stats[1] = (float)(1.0 / (sqrt(var) + (double)EPS_));
  }
}

// ---------------- final norm + prelu (bf16 in, f32 out) ---------------------
__global__ __launch_bounds__(256) void k_norm_f32(const unsigned* __restrict__ inU,
    const float* __restrict__ g, const float* __restrict__ be,
    const float* __restrict__ aP, const float* __restrict__ stats,
    float* __restrict__ out){
  float mean = stats[0], inv = stats[1], a = aP[0];
  int gid   = blockIdx.x*256 + threadIdx.x;
  int base8 = gid*8;
  int c0    = base8 & (D_-1);
  uint4 vin = *(const uint4*)&inU[gid*4];
  float4 g0 = *(const float4*)&g[c0],  g1 = *(const float4*)&g[c0+4];
  float4 e0 = *(const float4*)&be[c0], e1 = *(const float4*)&be[c0+4];
  float v[8];
  unpack2(vin.x, v[0], v[1]); unpack2(vin.y, v[2], v[3]);
  unpack2(vin.z, v[4], v[5]); unpack2(vin.w, v[6], v[7]);
  float gg[8] = {g0.x,g0.y,g0.z,g0.w,g1.x,g1.y,g1.z,g1.w};
  float eb[8] = {e0.x,e0.y,e0.z,e0.w,e1.x,e1.y,e1.z,e1.w};
  f32x4 o0, o1;
  #pragma unroll
  for (int i=0;i<8;i++){
    float tt = gg[i]*((v[i]-mean)*inv) + eb[i];
    tt = tt>=0.f ? tt : a*tt;
    if (i<4) o0[i] = tt; else o1[i-4] = tt;
  }
  *(f32x4*)&out[base8]     = o0;
  *(f32x4*)&out[base8 + 4] = o1;
}

// ---------------- launch ----------------

extern "C" void kernel_launch(void* const* d_in, const int* in_sizes, int n_in,
                              void* d_out, int out_size, void* d_ws, size_t ws_size,
                              hipStream_t stream){
  const float* x    = (const float*)d_in[0];
  const int*   knn  = (const int*)  d_in[1];
  const void*  mask =               d_in[2];
  const float* W0   = (const float*)d_in[3];
  const float* b0   = (const float*)d_in[4];
  const float* g0   = (const float*)d_in[5];
  const float* be0  = (const float*)d_in[6];
  const float* a0   = (const float*)d_in[7];
  const float* W1   = (const float*)d_in[8];
  const float* b1   = (const float*)d_in[9];
  const float* g1   = (const float*)d_in[10];
  const float* be1  = (const float*)d_in[11];
  const float* a1   = (const float*)d_in[12];
  float* out = (float*)d_out;

  char* w = (char*)d_ws;
  size_t off = 0;
  auto alloc = [&](size_t bytes)->void*{
    void* p = w + off; off = (off + bytes + 255) & ~(size_t)255; return p;
  };
  int*      degcnt  = (int*)     alloc(NT_*4);
  int*      rowptr  = (int*)     alloc((NT_+1)*4);
  int*      fillptr = (int*)     alloc(NT_*4);
  int*      col     = (int*)     alloc(E16_*4);
  float*    dinv    = (float*)   alloc(NT_*4);
  float*    partS   = (float*)   alloc(4096*4);
  float*    partQ   = (float*)   alloc(4096*4);
  float*    stats   = (float*)   alloc(4*4);
  int*      flag    = (int*)     alloc(4);
  short*    Ab      = (short*)   alloc((size_t)NP_*2);   // gemm output (bf16)
  unsigned* Bagg    = (unsigned*)alloc((size_t)NP_*2);   // agg output (bf16 pairs)
  short*    Wt0     = (short*)   alloc(256*256*2);
  short*    Wt1     = (short*)   alloc(256*256*2);

  // edge structure + weights
  hipLaunchKernelGGL(k_init,  dim3(NT_/256),  dim3(256), 0, stream, degcnt, (const unsigned int*)mask, flag);
  hipLaunchKernelGGL(k_deg,   dim3(E16_/256), dim3(256), 0, stream, knn, mask, flag, degcnt);
  hipLaunchKernelGGL(k_scan,  dim3(1),        dim3(1024),0, stream, degcnt, rowptr, fillptr, dinv);
  hipLaunchKernelGGL(k_fill,  dim3(E16_/256), dim3(256), 0, stream, knn, mask, flag, fillptr, col);
  hipLaunchKernelGGL(k_cvt_w, dim3(128),      dim3(256), 0, stream, W0, W1, Wt0, Wt1);

  // layer 0 (cvt_x fused into gemm staging)
  hipLaunchKernelGGL(k_gemm_x, dim3(512),     dim3(256), 0, stream, x, Wt0, Ab);
  hipLaunchKernelGGL(k_agg,    dim3(NT_/8),   dim3(256), 0, stream, Ab, rowptr, col, dinv, b0, Bagg, partS, partQ);
  hipLaunchKernelGGL(k_stats,  dim3(1),       dim3(1024),0, stream, partS, partQ, stats);

  // layer 1 (norm0+prelu fused into gemm staging)
  hipLaunchKernelGGL(k_gemm_n, dim3(512),     dim3(256), 0, stream, Bagg, g0, be0, a0, stats, Wt1, Ab);
  hipLaunchKernelGGL(k_agg,    dim3(NT_/8),   dim3(256), 0, stream, Ab, rowptr, col, dinv, b1, Bagg, partS, partQ);
  hipLaunchKernelGGL(k_stats,  dim3(1),       dim3(1024),0, stream, partS, partQ, stats);
  hipLaunchKernelGGL(k_norm_f32, dim3(NP_/2048), dim3(256), 0, stream, Bagg, g1, be1, a1, stats, out);
}

// Round 11
// 166.371 us; speedup vs baseline: 1.4515x; 1.0610x over previous
//
#include <hip/hip_runtime.h>
#include <hip/hip_bf16.h>
#include <stdint.h>

#define B_   8
#define N_   4096
#define K1_  17
#define D_   256
#define NT_  (B_*N_)          // 32768
#define E16_ (NT_*16)         // 524288
#define NP_  (NT_*D_)         // 8388608
#define EPS_ 1e-5f

typedef __attribute__((ext_vector_type(8))) short short8v;  // 8 bf16 (4 VGPR)
typedef __attribute__((ext_vector_type(4))) short short4v;
typedef __attribute__((ext_vector_type(4))) float f32x4;

// f32 -> bf16 RNE, pure C
__device__ __forceinline__ unsigned short f2bfu(float f){
  unsigned u = __float_as_uint(f);
  unsigned r = (u + 0x7FFFu + ((u>>16)&1u)) >> 16;
  return (unsigned short)r;
}
__device__ __forceinline__ short f2bf(float f){ return (short)f2bfu(f); }
__device__ __forceinline__ unsigned pkbf(float lo, float hi){
  return (unsigned)f2bfu(lo) | ((unsigned)f2bfu(hi) << 16);
}
__device__ __forceinline__ float bf2f(short s){
  return __uint_as_float(((unsigned)(unsigned short)s) << 16);
}
__device__ __forceinline__ void unpack2(unsigned u, float& lo, float& hi){
  lo = __uint_as_float(u << 16);
  hi = __uint_as_float(u & 0xFFFF0000u);
}

// ---------------- prep: weight transpose + degcnt zero + mask detect --------
// blocks 0..127: LDS-tiled transpose (even->W0, odd->W1)
// blocks 128..255: zero degcnt; block 128 also detects mask storage
__global__ __launch_bounds__(256) void k_prep(const float* __restrict__ W0,
                                              const float* __restrict__ W1,
                                              short* __restrict__ Wt0,
                                              short* __restrict__ Wt1,
                                              int* __restrict__ degcnt,
                                              const unsigned int* __restrict__ mw,
                                              int* __restrict__ flag){
  if (blockIdx.x < 128){
    const float* W  = (blockIdx.x & 1) ? W1  : W0;
    short*       Wt = (blockIdx.x & 1) ? Wt1 : Wt0;
    int tile = blockIdx.x >> 1;
    int ti = tile >> 3, tj = tile & 7;
    __shared__ float sm[32][33];
    int r = threadIdx.x >> 5, c = threadIdx.x & 31;
    #pragma unroll
    for (int i=0;i<4;i++)
      sm[r + i*8][c] = W[(ti*32 + r + i*8)*256 + tj*32 + c];
    __syncthreads();
    #pragma unroll
    for (int i=0;i<4;i++){
      int rr = r + i*8;
      Wt[(size_t)(tj*32 + rr)*256 + ti*32 + c] = f2bf(sm[c][rr]);
    }
  } else {
    int ib = blockIdx.x - 128;
    int i  = ib*256 + threadIdx.x;
    degcnt[i] = 0;
    if (ib == 0){
      __shared__ int s_int, s_f32;
      if (threadIdx.x==0){ s_int=1; s_f32=1; }
      __syncthreads();
      int bad_i=0, bad_f=0;
      #pragma unroll
      for (int j=0;j<4;j++){
        unsigned w = mw[threadIdx.x*4 + j];
        if (!(w==0u || w==1u))          bad_i=1;
        if (!(w==0u || w==0x3F800000u)) bad_f=1;
      }
      if (bad_i) atomicAnd(&s_int, 0);
      if (bad_f) atomicAnd(&s_f32, 0);
      __syncthreads();
      if (threadIdx.x==0) *flag = s_int ? 0 : (s_f32 ? 1 : 2);
    }
  }
}

__device__ __forceinline__ bool mask_at(const void* maskp, int f, int idx){
  if (f==0) return ((const int*)maskp)[idx] != 0;
  if (f==1) return ((const float*)maskp)[idx] != 0.0f;
  return ((const unsigned char*)maskp)[idx] != 0;
}

__global__ void k_deg(const int* __restrict__ knn, const void* __restrict__ maskp,
                      const int* __restrict__ flag, int* __restrict__ degcnt){
  int f = *flag;
  int e = blockIdx.x*blockDim.x + threadIdx.x;
  if (e >= E16_) return;
  int node = e >> 4;
  int k    = (e & 15) + 1;
  int idx  = node*K1_ + k;
  if (mask_at(maskp, f, idx)){
    int b   = node >> 12;
    int dst = knn[idx] + (b<<12);
    atomicAdd(&degcnt[dst], 1);
  }
}

__global__ void k_scan(const int* __restrict__ degcnt, int* __restrict__ rowptr,
                       int* __restrict__ fillptr, float* __restrict__ dinv){
  __shared__ int sm[1024];
  int t = threadIdx.x;
  int base = t*32;
  int loc[32]; int tot = 0;
  #pragma unroll
  for (int i=0;i<32;i++){ loc[i] = degcnt[base+i]; tot += loc[i]; }
  sm[t] = tot; __syncthreads();
  for (int off=1; off<1024; off<<=1){
    int v = (t>=off) ? sm[t-off] : 0;
    __syncthreads();
    sm[t] += v;
    __syncthreads();
  }
  int run = sm[t] - tot;
  #pragma unroll
  for (int i=0;i<32;i++){
    int v = base+i;
    rowptr[v]  = run;
    fillptr[v] = run;
    dinv[v]    = rsqrtf((float)loc[i] + 1.0f);
    run += loc[i];
  }
  if (t==1023) rowptr[NT_] = run;
}

__global__ void k_fill(const int* __restrict__ knn, const void* __restrict__ maskp,
                       const int* __restrict__ flag, int* __restrict__ fillptr,
                       int* __restrict__ col){
  int f = *flag;
  int e = blockIdx.x*blockDim.x + threadIdx.x;
  if (e >= E16_) return;
  int node = e >> 4;
  int k    = (e & 15) + 1;
  int idx  = node*K1_ + k;
  if (mask_at(maskp, f, idx)){
    int b   = node >> 12;
    int dst = knn[idx] + (b<<12);
    int pos = atomicAdd(&fillptr[dst], 1);
    col[pos] = node;
  }
}

// ---------------- MFMA GEMM (m97 structure), fused input transforms --------
// 256 thr = 4 waves (2x2). Tile 128x128, BK=64, 4 K-steps. A and B staged in
// LDS via coalesced 8-thread/row loads; chunk swizzle ^(row&7) on write+read.
// Prefetch next K-step between barrier and compute.

// layer 0: A staged from x (f32, row stride 512), bf16-converted in staging.
__global__ __launch_bounds__(256, 3) void k_gemm_x(const float* __restrict__ X,
                                                   const short* __restrict__ Wt,
                                                   short* __restrict__ C){
  __shared__ short lA[128*64];   // 16KB
  __shared__ short lB[128*64];   // 16KB
  int lb     = (int)(blockIdx.x & 7)*64 + (int)(blockIdx.x >> 3);  // XCD chunk
  int rowblk = lb >> 1, half = lb & 1;
  int rowB = rowblk*128, colB = half*128;

  int t    = threadIdx.x;
  int wave = t >> 6, lane = t & 63;
  int lr   = lane & 15, qg = lane >> 4;
  int wr   = wave >> 1, wc = wave & 1;

  f32x4 acc[4][4];
  #pragma unroll
  for (int m=0;m<4;m++)
    #pragma unroll
    for (int n=0;n<4;n++) acc[m][n] = (f32x4){0.f,0.f,0.f,0.f};

  int srow[4], sch[4];
  #pragma unroll
  for (int i=0;i<4;i++){ int e = t + i*256; srow[i] = e>>3; sch[i] = e&7; }

  float4 rax[4], ray[4]; uint4 rb[4];
  #pragma unroll
  for (int i=0;i<4;i++){
    const float* ap = X + (size_t)(rowB+srow[i])*512 + sch[i]*8;
    rax[i] = *(const float4*)ap;
    ray[i] = *(const float4*)(ap+4);
    rb[i]  = *(const uint4*)(Wt + (size_t)(colB+srow[i])*256 + sch[i]*8);
  }

  for (int kc=0; kc<4; kc++){
    if (kc) __syncthreads();
    #pragma unroll
    for (int i=0;i<4;i++){
      int ph = srow[i]*8 + (sch[i] ^ (srow[i]&7));
      uint4 cv;
      cv.x = pkbf(rax[i].x, rax[i].y); cv.y = pkbf(rax[i].z, rax[i].w);
      cv.z = pkbf(ray[i].x, ray[i].y); cv.w = pkbf(ray[i].z, ray[i].w);
      *(uint4*)(lA + ph*8) = cv;
      *(uint4*)(lB + ph*8) = rb[i];
    }
    __syncthreads();
    if (kc < 3){
      #pragma unroll
      for (int i=0;i<4;i++){
        const float* ap = X + (size_t)(rowB+srow[i])*512 + (kc+1)*64 + sch[i]*8;
        rax[i] = *(const float4*)ap;
        ray[i] = *(const float4*)(ap+4);
        rb[i]  = *(const uint4*)(Wt + (size_t)(colB+srow[i])*256 + (kc+1)*64 + sch[i]*8);
      }
    }
    #pragma unroll
    for (int ks=0; ks<2; ks++){
      short8v af[4], bfr[4];
      #pragma unroll
      for (int m=0;m<4;m++){
        int row = wr*64 + m*16 + lr;
        af[m] = *(const short8v*)(lA + (row*8 + ((ks*4+qg) ^ (row&7)))*8);
      }
      #pragma unroll
      for (int n=0;n<4;n++){
        int coln = wc*64 + n*16 + lr;
        bfr[n] = *(const short8v*)(lB + (coln*8 + ((ks*4+qg) ^ (coln&7)))*8);
      }
      #pragma unroll
      for (int m=0;m<4;m++)
        #pragma unroll
        for (int n=0;n<4;n++)
          acc[m][n] = __builtin_amdgcn_mfma_f32_16x16x32_bf16(af[m], bfr[n], acc[m][n], 0, 0, 0);
    }
  }

  #pragma unroll
  for (int m=0;m<4;m++){
    int crow = rowB + wr*64 + m*16 + qg*4;
    #pragma unroll
    for (int n=0;n<4;n++){
      int ccol = colB + wc*64 + n*16 + lr;
      #pragma unroll
      for (int r=0;r<4;r++)
        C[(size_t)(crow + r)*256 + ccol] = f2bf(acc[m][n][r]);
    }
  }
}

// layer 1: A staged from Bagg (bf16 pairs) with fused graph-norm + PReLU.
__global__ __launch_bounds__(256, 3) void k_gemm_n(const unsigned* __restrict__ BaggU,
                                                   const float* __restrict__ g,
                                                   const float* __restrict__ be,
                                                   const float* __restrict__ aP,
                                                   const float* __restrict__ stats,
                                                   const short* __restrict__ Wt,
                                                   short* __restrict__ C){
  float mean = stats[0], inv = stats[1], a = aP[0];
  __shared__ short lA[128*64];
  __shared__ short lB[128*64];
  int lb     = (int)(blockIdx.x & 7)*64 + (int)(blockIdx.x >> 3);
  int rowblk = lb >> 1, half = lb & 1;
  int rowB = rowblk*128, colB = half*128;

  int t    = threadIdx.x;
  int wave = t >> 6, lane = t & 63;
  int lr   = lane & 15, qg = lane >> 4;
  int wr   = wave >> 1, wc = wave & 1;

  f32x4 acc[4][4];
  #pragma unroll
  for (int m=0;m<4;m++)
    #pragma unroll
    for (int n=0;n<4;n++) acc[m][n] = (f32x4){0.f,0.f,0.f,0.f};

  int srow[4], sch[4];
  #pragma unroll
  for (int i=0;i<4;i++){ int e = t + i*256; srow[i] = e>>3; sch[i] = e&7; }

  uint4 ra[4], rb[4];
  #pragma unroll
  for (int i=0;i<4;i++){
    ra[i] = *(const uint4*)(BaggU + (size_t)(rowB+srow[i])*128 + sch[i]*4);
    rb[i] = *(const uint4*)(Wt + (size_t)(colB+srow[i])*256 + sch[i]*8);
  }

  for (int kc=0; kc<4; kc++){
    if (kc) __syncthreads();
    #pragma unroll
    for (int i=0;i<4;i++){
      int ph = srow[i]*8 + (sch[i] ^ (srow[i]&7));
      int c0 = kc*64 + sch[i]*8;
      float4 g0 = *(const float4*)&g[c0],  g1 = *(const float4*)&g[c0+4];
      float4 e0 = *(const float4*)&be[c0], e1 = *(const float4*)&be[c0+4];
      float v[8];
      unpack2(ra[i].x, v[0], v[1]); unpack2(ra[i].y, v[2], v[3]);
      unpack2(ra[i].z, v[4], v[5]); unpack2(ra[i].w, v[6], v[7]);
      float gg[8] = {g0.x,g0.y,g0.z,g0.w,g1.x,g1.y,g1.z,g1.w};
      float eb[8] = {e0.x,e0.y,e0.z,e0.w,e1.x,e1.y,e1.z,e1.w};
      float o[8];
      #pragma unroll
      for (int j=0;j<8;j++){
        float tt = gg[j]*((v[j]-mean)*inv) + eb[j];
        o[j] = tt>=0.f ? tt : a*tt;
      }
      uint4 cv;
      cv.x = pkbf(o[0],o[1]); cv.y = pkbf(o[2],o[3]);
      cv.z = pkbf(o[4],o[5]); cv.w = pkbf(o[6],o[7]);
      *(uint4*)(lA + ph*8) = cv;
      *(uint4*)(lB + ph*8) = rb[i];
    }
    __syncthreads();
    if (kc < 3){
      #pragma unroll
      for (int i=0;i<4;i++){
        ra[i] = *(const uint4*)(BaggU + (size_t)(rowB+srow[i])*128 + (kc+1)*32 + sch[i]*4);
        rb[i] = *(const uint4*)(Wt + (size_t)(colB+srow[i])*256 + (kc+1)*64 + sch[i]*8);
      }
    }
    #pragma unroll
    for (int ks=0; ks<2; ks++){
      short8v af[4], bfr[4];
      #pragma unroll
      for (int m=0;m<4;m++){
        int row = wr*64 + m*16 + lr;
        af[m] = *(const short8v*)(lA + (row*8 + ((ks*4+qg) ^ (row&7)))*8);
      }
      #pragma unroll
      for (int n=0;n<4;n++){
        int coln = wc*64 + n*16 + lr;
        bfr[n] = *(const short8v*)(lB + (coln*8 + ((ks*4+qg) ^ (coln&7)))*8);
      }
      #pragma unroll
      for (int m=0;m<4;m++)
        #pragma unroll
        for (int n=0;n<4;n++)
          acc[m][n] = __builtin_amdgcn_mfma_f32_16x16x32_bf16(af[m], bfr[n], acc[m][n], 0, 0, 0);
    }
  }

  #pragma unroll
  for (int m=0;m<4;m++){
    int crow = rowB + wr*64 + m*16 + qg*4;
    #pragma unroll
    for (int n=0;n<4;n++){
      int ccol = colB + wc*64 + n*16 + lr;
      #pragma unroll
      for (int r=0;r<4;r++)
        C[(size_t)(crow + r)*256 + ccol] = f2bf(acc[m][n][r]);
    }
  }
}

// ---------------- aggregation: 32 lanes/node, parallel gather pipeline ------
// Lane-distributed index prefetch: lanes load col[] and dinv[] in parallel,
// broadcast via shfl -> all neighbor-row loads issue without a serial chain.
__global__ __launch_bounds__(256) void k_agg(const short* __restrict__ Ab,
    const int* __restrict__ rowptr, const int* __restrict__ col,
    const float* __restrict__ dinv, const float* __restrict__ bvec,
    unsigned* __restrict__ outU, float* __restrict__ partS, float* __restrict__ partQ){
  int bid  = (int)(blockIdx.x & 7) * 512 + (int)(blockIdx.x >> 3);  // XCD swizzle
  int node = bid*8 + (threadIdx.x >> 5);
  int sub  = threadIdx.x & 31;
  int c0   = sub*8;
  float dv = dinv[node];

  float acc[8];
  {
    short8v s = *(const short8v*)&Ab[(size_t)node*256 + c0];
    #pragma unroll
    for (int i=0;i<8;i++) acc[i] = dv * bf2f(s[i]);
  }
  int j0 = rowptr[node], j1 = rowptr[node+1];
  for (int base=j0; base<j1; base+=32){
    int n = j1 - base; n = n < 32 ? n : 32;
    int   myc = (sub < n) ? col[base+sub] : 0;
    float myd = (sub < n) ? dinv[myc]     : 0.f;
    for (int j=0;j<n;j++){
      int   s  = __shfl(myc, j, 32);
      float ds = __shfl(myd, j, 32);
      short8v nb = *(const short8v*)&Ab[(size_t)s*256 + c0];
      #pragma unroll
      for (int i=0;i<8;i++) acc[i] += ds * bf2f(nb[i]);
    }
  }
  float sum=0.f, sq=0.f;
  float o[8];
  #pragma unroll
  for (int i=0;i<8;i++){
    float v = dv*acc[i] + bvec[c0+i];
    o[i] = v;
    sum += v; sq += v*v;
  }
  uint4 ov;
  ov.x = pkbf(o[0],o[1]); ov.y = pkbf(o[2],o[3]);
  ov.z = pkbf(o[4],o[5]); ov.w = pkbf(o[6],o[7]);
  *(uint4*)&outU[(size_t)node*128 + sub*4] = ov;

  #pragma unroll
  for (int off=16; off>0; off>>=1){
    sum += __shfl_down(sum, off, 32);
    sq  += __shfl_down(sq,  off, 32);
  }
  __shared__ float ls1[8], ls2[8];
  if (sub==0){ ls1[threadIdx.x>>5]=sum; ls2[threadIdx.x>>5]=sq; }
  __syncthreads();
  if (threadIdx.x==0){
    float a=0.f, b=0.f;
    #pragma unroll
    for (int i=0;i<8;i++){ a+=ls1[i]; b+=ls2[i]; }
    partS[bid]=a; partQ[bid]=b;
  }
}

// ---------------- stats over 4096 per-block partials (double accum) ---------
__global__ void k_stats(const float* __restrict__ partS, const float* __restrict__ partQ,
                        float* __restrict__ stats){
  __shared__ double s1[1024], s2[1024];
  int t = threadIdx.x;
  double a=0.0, b=0.0;
  for (int i=t; i<4096; i+=1024){ a += (double)partS[i]; b += (double)partQ[i]; }
  s1[t]=a; s2[t]=b; __syncthreads();
  for (int off=512; off>0; off>>=1){
    if (t<off){ s1[t]+=s1[t+off]; s2[t]+=s2[t+off]; }
    __syncthreads();
  }
  if (t==0){
    double mean = s1[0] / (double)NP_;
    double var  = s2[0] / (double)NP_ - mean*mean;
    var = var > 0.0 ? var : 0.0;
    stats[0] = (float)mean;
    stats[1] = (float)(1.0 / (sqrt(var) + (double)EPS_));
  }
}

// ---------------- final norm + prelu (bf16 in, f32 out) ---------------------
__global__ __launch_bounds__(256) void k_norm_f32(const unsigned* __restrict__ inU,
    const float* __restrict__ g, const float* __restrict__ be,
    const float* __restrict__ aP, const float* __restrict__ stats,
    float* __restrict__ out){
  float mean = stats[0], inv = stats[1], a = aP[0];
  int gid   = blockIdx.x*256 + threadIdx.x;
  int base8 = gid*8;
  int c0    = base8 & (D_-1);
  uint4 vin = *(const uint4*)&inU[gid*4];
  float4 g0 = *(const float4*)&g[c0],  g1 = *(const float4*)&g[c0+4];
  float4 e0 = *(const float4*)&be[c0], e1 = *(const float4*)&be[c0+4];
  float v[8];
  unpack2(vin.x, v[0], v[1]); unpack2(vin.y, v[2], v[3]);
  unpack2(vin.z, v[4], v[5]); unpack2(vin.w, v[6], v[7]);
  float gg[8] = {g0.x,g0.y,g0.z,g0.w,g1.x,g1.y,g1.z,g1.w};
  float eb[8] = {e0.x,e0.y,e0.z,e0.w,e1.x,e1.y,e1.z,e1.w};
  f32x4 o0, o1;
  #pragma unroll
  for (int i=0;i<8;i++){
    float tt = gg[i]*((v[i]-mean)*inv) + eb[i];
    tt = tt>=0.f ? tt : a*tt;
    if (i<4) o0[i] = tt; else o1[i-4] = tt;
  }
  *(f32x4*)&out[base8]     = o0;
  *(f32x4*)&out[base8 + 4] = o1;
}

// ---------------- launch ----------------

extern "C" void kernel_launch(void* const* d_in, const int* in_sizes, int n_in,
                              void* d_out, int out_size, void* d_ws, size_t ws_size,
                              hipStream_t stream){
  const float* x    = (const float*)d_in[0];
  const int*   knn  = (const int*)  d_in[1];
  const void*  mask =               d_in[2];
  const float* W0   = (const float*)d_in[3];
  const float* b0   = (const float*)d_in[4];
  const float* g0   = (const float*)d_in[5];
  const float* be0  = (const float*)d_in[6];
  const float* a0   = (const float*)d_in[7];
  const float* W1   = (const float*)d_in[8];
  const float* b1   = (const float*)d_in[9];
  const float* g1   = (const float*)d_in[10];
  const float* be1  = (const float*)d_in[11];
  const float* a1   = (const float*)d_in[12];
  float* out = (float*)d_out;

  char* w = (char*)d_ws;
  size_t off = 0;
  auto alloc = [&](size_t bytes)->void*{
    void* p = w + off; off = (off + bytes + 255) & ~(size_t)255; return p;
  };
  int*      degcnt  = (int*)     alloc(NT_*4);
  int*      rowptr  = (int*)     alloc((NT_+1)*4);
  int*      fillptr = (int*)     alloc(NT_*4);
  int*      col     = (int*)     alloc(E16_*4);
  float*    dinv    = (float*)   alloc(NT_*4);
  float*    partS   = (float*)   alloc(4096*4);
  float*    partQ   = (float*)   alloc(4096*4);
  float*    stats   = (float*)   alloc(4*4);
  int*      flag    = (int*)     alloc(4);
  short*    Ab      = (short*)   alloc((size_t)NP_*2);   // gemm output (bf16)
  unsigned* Bagg    = (unsigned*)alloc((size_t)NP_*2);   // agg output (bf16 pairs)
  short*    Wt0     = (short*)   alloc(256*256*2);
  short*    Wt1     = (short*)   alloc(256*256*2);

  // prep (weights + degcnt zero + detect), then edge structure
  hipLaunchKernelGGL(k_prep,  dim3(256),      dim3(256), 0, stream, W0, W1, Wt0, Wt1,
                     degcnt, (const unsigned int*)mask, flag);
  hipLaunchKernelGGL(k_deg,   dim3(E16_/256), dim3(256), 0, stream, knn, mask, flag, degcnt);
  hipLaunchKernelGGL(k_scan,  dim3(1),        dim3(1024),0, stream, degcnt, rowptr, fillptr, dinv);
  hipLaunchKernelGGL(k_fill,  dim3(E16_/256), dim3(256), 0, stream, knn, mask, flag, fillptr, col);

  // layer 0 (cvt_x fused into gemm staging)
  hipLaunchKernelGGL(k_gemm_x, dim3(512),     dim3(256), 0, stream, x, Wt0, Ab);
  hipLaunchKernelGGL(k_agg,    dim3(NT_/8),   dim3(256), 0, stream, Ab, rowptr, col, dinv, b0, Bagg, partS, partQ);
  hipLaunchKernelGGL(k_stats,  dim3(1),       dim3(1024),0, stream, partS, partQ, stats);

  // layer 1 (norm0+prelu fused into gemm staging)
  hipLaunchKernelGGL(k_gemm_n, dim3(512),     dim3(256), 0, stream, Bagg, g0, be0, a0, stats, Wt1, Ab);
  hipLaunchKernelGGL(k_agg,    dim3(NT_/8),   dim3(256), 0, stream, Ab, rowptr, col, dinv, b1, Bagg, partS, partQ);
  hipLaunchKernelGGL(k_stats,  dim3(1),       dim3(1024),0, stream, partS, partQ, stats);
  hipLaunchKernelGGL(k_norm_f32, dim3(NP_/2048), dim3(256), 0, stream, Bagg, g1, be1, a1, stats, out);
}

// Round 12
// 159.797 us; speedup vs baseline: 1.5112x; 1.0411x over previous
//
#include <hip/hip_runtime.h>
#include <hip/hip_bf16.h>
#include <stdint.h>

#define B_   8
#define N_   4096
#define K1_  17
#define D_   256
#define NT_  (B_*N_)          // 32768
#define E16_ (NT_*16)         // 524288
#define NP_  (NT_*D_)         // 8388608
#define EPS_ 1e-5f

typedef __attribute__((ext_vector_type(8))) short short8v;  // 8 bf16 (4 VGPR)
typedef __attribute__((ext_vector_type(4))) short short4v;
typedef __attribute__((ext_vector_type(4))) float f32x4;

// f32 -> bf16 RNE, pure C
__device__ __forceinline__ unsigned short f2bfu(float f){
  unsigned u = __float_as_uint(f);
  unsigned r = (u + 0x7FFFu + ((u>>16)&1u)) >> 16;
  return (unsigned short)r;
}
__device__ __forceinline__ short f2bf(float f){ return (short)f2bfu(f); }
__device__ __forceinline__ unsigned pkbf(float lo, float hi){
  return (unsigned)f2bfu(lo) | ((unsigned)f2bfu(hi) << 16);
}
__device__ __forceinline__ float bf2f(short s){
  return __uint_as_float(((unsigned)(unsigned short)s) << 16);
}
__device__ __forceinline__ void unpack2(unsigned u, float& lo, float& hi){
  lo = __uint_as_float(u << 16);
  hi = __uint_as_float(u & 0xFFFF0000u);
}

// ---------------- prep: weight transpose + degcnt zero + mask detect --------
__global__ __launch_bounds__(256) void k_prep(const float* __restrict__ W0,
                                              const float* __restrict__ W1,
                                              short* __restrict__ Wt0,
                                              short* __restrict__ Wt1,
                                              int* __restrict__ degcnt,
                                              const unsigned int* __restrict__ mw,
                                              int* __restrict__ flag){
  if (blockIdx.x < 128){
    const float* W  = (blockIdx.x & 1) ? W1  : W0;
    short*       Wt = (blockIdx.x & 1) ? Wt1 : Wt0;
    int tile = blockIdx.x >> 1;
    int ti = tile >> 3, tj = tile & 7;
    __shared__ float sm[32][33];
    int r = threadIdx.x >> 5, c = threadIdx.x & 31;
    #pragma unroll
    for (int i=0;i<4;i++)
      sm[r + i*8][c] = W[(ti*32 + r + i*8)*256 + tj*32 + c];
    __syncthreads();
    #pragma unroll
    for (int i=0;i<4;i++){
      int rr = r + i*8;
      Wt[(size_t)(tj*32 + rr)*256 + ti*32 + c] = f2bf(sm[c][rr]);
    }
  } else {
    int ib = blockIdx.x - 128;
    int i  = ib*256 + threadIdx.x;
    degcnt[i] = 0;
    if (ib == 0){
      __shared__ int s_int, s_f32;
      if (threadIdx.x==0){ s_int=1; s_f32=1; }
      __syncthreads();
      int bad_i=0, bad_f=0;
      #pragma unroll
      for (int j=0;j<4;j++){
        unsigned w = mw[threadIdx.x*4 + j];
        if (!(w==0u || w==1u))          bad_i=1;
        if (!(w==0u || w==0x3F800000u)) bad_f=1;
      }
      if (bad_i) atomicAnd(&s_int, 0);
      if (bad_f) atomicAnd(&s_f32, 0);
      __syncthreads();
      if (threadIdx.x==0) *flag = s_int ? 0 : (s_f32 ? 1 : 2);
    }
  }
}

__device__ __forceinline__ bool mask_at(const void* maskp, int f, int idx){
  if (f==0) return ((const int*)maskp)[idx] != 0;
  if (f==1) return ((const float*)maskp)[idx] != 0.0f;
  return ((const unsigned char*)maskp)[idx] != 0;
}

__global__ void k_deg(const int* __restrict__ knn, const void* __restrict__ maskp,
                      const int* __restrict__ flag, int* __restrict__ degcnt){
  int f = *flag;
  int e = blockIdx.x*blockDim.x + threadIdx.x;
  if (e >= E16_) return;
  int node = e >> 4;
  int k    = (e & 15) + 1;
  int idx  = node*K1_ + k;
  if (mask_at(maskp, f, idx)){
    int b   = node >> 12;
    int dst = knn[idx] + (b<<12);
    atomicAdd(&degcnt[dst], 1);
  }
}

// wave-shfl scan: 1024 thr = 16 waves; 6 shfl steps + ONE barrier (was 20)
__global__ void k_scan(const int* __restrict__ degcnt, int* __restrict__ rowptr,
                       int* __restrict__ fillptr, float* __restrict__ dinv){
  __shared__ int wsum[16];
  int t = threadIdx.x;
  int lane = t & 63, wid = t >> 6;
  int base = t*32;
  int loc[32]; int tot = 0;
  #pragma unroll
  for (int i=0;i<32;i++){ loc[i] = degcnt[base+i]; tot += loc[i]; }
  int inc = tot;
  #pragma unroll
  for (int off=1; off<64; off<<=1){
    int v = __shfl_up(inc, off, 64);
    if (lane >= off) inc += v;
  }
  if (lane == 63) wsum[wid] = inc;
  __syncthreads();
  int woff = 0;
  #pragma unroll
  for (int i=0;i<16;i++) if (i < wid) woff += wsum[i];
  int run = woff + inc - tot;          // exclusive prefix
  #pragma unroll
  for (int i=0;i<32;i++){
    int v = base+i;
    rowptr[v]  = run;
    fillptr[v] = run;
    dinv[v]    = rsqrtf((float)loc[i] + 1.0f);
    run += loc[i];
  }
  if (t==1023) rowptr[NT_] = run;
}

// ---------------- fused: MFMA GEMM layer-0 (blocks 0..511) + CSR fill (512..2559)
// gemm: 256 thr = 4 waves (2x2), tile 128x128, BK=64, LDS-staged, chunk
// swizzle ^(row&7) write+read, next-K prefetch. fill: independent of gemm,
// runs concurrently in the same dispatch (hides its ~6us).
__global__ __launch_bounds__(256, 3) void k_gemm_x_fill(const float* __restrict__ X,
                                                        const short* __restrict__ Wt,
                                                        short* __restrict__ C,
                                                        const int* __restrict__ knn,
                                                        const void* __restrict__ maskp,
                                                        const int* __restrict__ flag,
                                                        int* __restrict__ fillptr,
                                                        int* __restrict__ col){
  __shared__ short lA[128*64];   // 16KB
  __shared__ short lB[128*64];   // 16KB
  if (blockIdx.x >= 512){
    // ---- CSR fill ----
    int f = *flag;
    int e = (blockIdx.x - 512)*256 + threadIdx.x;
    int node = e >> 4;
    int k    = (e & 15) + 1;
    int idx  = node*K1_ + k;
    if (mask_at(maskp, f, idx)){
      int b   = node >> 12;
      int dst = knn[idx] + (b<<12);
      int pos = atomicAdd(&fillptr[dst], 1);
      col[pos] = node;
    }
    return;
  }
  // ---- GEMM layer 0 ----
  int lb     = (int)(blockIdx.x & 7)*64 + (int)(blockIdx.x >> 3);  // XCD chunk
  int rowblk = lb >> 1, half = lb & 1;
  int rowB = rowblk*128, colB = half*128;

  int t    = threadIdx.x;
  int wave = t >> 6, lane = t & 63;
  int lr   = lane & 15, qg = lane >> 4;
  int wr   = wave >> 1, wc = wave & 1;

  f32x4 acc[4][4];
  #pragma unroll
  for (int m=0;m<4;m++)
    #pragma unroll
    for (int n=0;n<4;n++) acc[m][n] = (f32x4){0.f,0.f,0.f,0.f};

  int srow[4], sch[4];
  #pragma unroll
  for (int i=0;i<4;i++){ int e = t + i*256; srow[i] = e>>3; sch[i] = e&7; }

  float4 rax[4], ray[4]; uint4 rb[4];
  #pragma unroll
  for (int i=0;i<4;i++){
    const float* ap = X + (size_t)(rowB+srow[i])*512 + sch[i]*8;
    rax[i] = *(const float4*)ap;
    ray[i] = *(const float4*)(ap+4);
    rb[i]  = *(const uint4*)(Wt + (size_t)(colB+srow[i])*256 + sch[i]*8);
  }

  for (int kc=0; kc<4; kc++){
    if (kc) __syncthreads();
    #pragma unroll
    for (int i=0;i<4;i++){
      int ph = srow[i]*8 + (sch[i] ^ (srow[i]&7));
      uint4 cv;
      cv.x = pkbf(rax[i].x, rax[i].y); cv.y = pkbf(rax[i].z, rax[i].w);
      cv.z = pkbf(ray[i].x, ray[i].y); cv.w = pkbf(ray[i].z, ray[i].w);
      *(uint4*)(lA + ph*8) = cv;
      *(uint4*)(lB + ph*8) = rb[i];
    }
    __syncthreads();
    if (kc < 3){
      #pragma unroll
      for (int i=0;i<4;i++){
        const float* ap = X + (size_t)(rowB+srow[i])*512 + (kc+1)*64 + sch[i]*8;
        rax[i] = *(const float4*)ap;
        ray[i] = *(const float4*)(ap+4);
        rb[i]  = *(const uint4*)(Wt + (size_t)(colB+srow[i])*256 + (kc+1)*64 + sch[i]*8);
      }
    }
    #pragma unroll
    for (int ks=0; ks<2; ks++){
      short8v af[4], bfr[4];
      #pragma unroll
      for (int m=0;m<4;m++){
        int row = wr*64 + m*16 + lr;
        af[m] = *(const short8v*)(lA + (row*8 + ((ks*4+qg) ^ (row&7)))*8);
      }
      #pragma unroll
      for (int n=0;n<4;n++){
        int coln = wc*64 + n*16 + lr;
        bfr[n] = *(const short8v*)(lB + (coln*8 + ((ks*4+qg) ^ (coln&7)))*8);
      }
      #pragma unroll
      for (int m=0;m<4;m++)
        #pragma unroll
        for (int n=0;n<4;n++)
          acc[m][n] = __builtin_amdgcn_mfma_f32_16x16x32_bf16(af[m], bfr[n], acc[m][n], 0, 0, 0);
    }
  }

  #pragma unroll
  for (int m=0;m<4;m++){
    int crow = rowB + wr*64 + m*16 + qg*4;
    #pragma unroll
    for (int n=0;n<4;n++){
      int ccol = colB + wc*64 + n*16 + lr;
      #pragma unroll
      for (int r=0;r<4;r++)
        C[(size_t)(crow + r)*256 + ccol] = f2bf(acc[m][n][r]);
    }
  }
}

// layer 1 GEMM: A staged from Bagg (bf16 pairs) with fused graph-norm + PReLU.
__global__ __launch_bounds__(256, 3) void k_gemm_n(const unsigned* __restrict__ BaggU,
                                                   const float* __restrict__ g,
                                                   const float* __restrict__ be,
                                                   const float* __restrict__ aP,
                                                   const float* __restrict__ stats,
                                                   const short* __restrict__ Wt,
                                                   short* __restrict__ C){
  float mean = stats[0], inv = stats[1], a = aP[0];
  __shared__ short lA[128*64];
  __shared__ short lB[128*64];
  int lb     = (int)(blockIdx.x & 7)*64 + (int)(blockIdx.x >> 3);
  int rowblk = lb >> 1, half = lb & 1;
  int rowB = rowblk*128, colB = half*128;

  int t    = threadIdx.x;
  int wave = t >> 6, lane = t & 63;
  int lr   = lane & 15, qg = lane >> 4;
  int wr   = wave >> 1, wc = wave & 1;

  f32x4 acc[4][4];
  #pragma unroll
  for (int m=0;m<4;m++)
    #pragma unroll
    for (int n=0;n<4;n++) acc[m][n] = (f32x4){0.f,0.f,0.f,0.f};

  int srow[4], sch[4];
  #pragma unroll
  for (int i=0;i<4;i++){ int e = t + i*256; srow[i] = e>>3; sch[i] = e&7; }

  uint4 ra[4], rb[4];
  #pragma unroll
  for (int i=0;i<4;i++){
    ra[i] = *(const uint4*)(BaggU + (size_t)(rowB+srow[i])*128 + sch[i]*4);
    rb[i] = *(const uint4*)(Wt + (size_t)(colB+srow[i])*256 + sch[i]*8);
  }

  for (int kc=0; kc<4; kc++){
    if (kc) __syncthreads();
    #pragma unroll
    for (int i=0;i<4;i++){
      int ph = srow[i]*8 + (sch[i] ^ (srow[i]&7));
      int c0 = kc*64 + sch[i]*8;
      float4 g0 = *(const float4*)&g[c0],  g1 = *(const float4*)&g[c0+4];
      float4 e0 = *(const float4*)&be[c0], e1 = *(const float4*)&be[c0+4];
      float v[8];
      unpack2(ra[i].x, v[0], v[1]); unpack2(ra[i].y, v[2], v[3]);
      unpack2(ra[i].z, v[4], v[5]); unpack2(ra[i].w, v[6], v[7]);
      float gg[8] = {g0.x,g0.y,g0.z,g0.w,g1.x,g1.y,g1.z,g1.w};
      float eb[8] = {e0.x,e0.y,e0.z,e0.w,e1.x,e1.y,e1.z,e1.w};
      float o[8];
      #pragma unroll
      for (int j=0;j<8;j++){
        float tt = gg[j]*((v[j]-mean)*inv) + eb[j];
        o[j] = tt>=0.f ? tt : a*tt;
      }
      uint4 cv;
      cv.x = pkbf(o[0],o[1]); cv.y = pkbf(o[2],o[3]);
      cv.z = pkbf(o[4],o[5]); cv.w = pkbf(o[6],o[7]);
      *(uint4*)(lA + ph*8) = cv;
      *(uint4*)(lB + ph*8) = rb[i];
    }
    __syncthreads();
    if (kc < 3){
      #pragma unroll
      for (int i=0;i<4;i++){
        ra[i] = *(const uint4*)(BaggU + (size_t)(rowB+srow[i])*128 + (kc+1)*32 + sch[i]*4);
        rb[i] = *(const uint4*)(Wt + (size_t)(colB+srow[i])*256 + (kc+1)*64 + sch[i]*8);
      }
    }
    #pragma unroll
    for (int ks=0; ks<2; ks++){
      short8v af[4], bfr[4];
      #pragma unroll
      for (int m=0;m<4;m++){
        int row = wr*64 + m*16 + lr;
        af[m] = *(const short8v*)(lA + (row*8 + ((ks*4+qg) ^ (row&7)))*8);
      }
      #pragma unroll
      for (int n=0;n<4;n++){
        int coln = wc*64 + n*16 + lr;
        bfr[n] = *(const short8v*)(lB + (coln*8 + ((ks*4+qg) ^ (coln&7)))*8);
      }
      #pragma unroll
      for (int m=0;m<4;m++)
        #pragma unroll
        for (int n=0;n<4;n++)
          acc[m][n] = __builtin_amdgcn_mfma_f32_16x16x32_bf16(af[m], bfr[n], acc[m][n], 0, 0, 0);
    }
  }

  #pragma unroll
  for (int m=0;m<4;m++){
    int crow = rowB + wr*64 + m*16 + qg*4;
    #pragma unroll
    for (int n=0;n<4;n++){
      int ccol = colB + wc*64 + n*16 + lr;
      #pragma unroll
      for (int r=0;r<4;r++)
        C[(size_t)(crow + r)*256 + ccol] = f2bf(acc[m][n][r]);
    }
  }
}

// ---------------- aggregation: 32 lanes/node, parallel gather pipeline ------
__global__ __launch_bounds__(256) void k_agg(const short* __restrict__ Ab,
    const int* __restrict__ rowptr, const int* __restrict__ col,
    const float* __restrict__ dinv, const float* __restrict__ bvec,
    unsigned* __restrict__ outU, float* __restrict__ partS, float* __restrict__ partQ){
  int bid  = (int)(blockIdx.x & 7) * 512 + (int)(blockIdx.x >> 3);  // XCD swizzle
  int node = bid*8 + (threadIdx.x >> 5);
  int sub  = threadIdx.x & 31;
  int c0   = sub*8;
  float dv = dinv[node];

  float acc[8];
  {
    short8v s = *(const short8v*)&Ab[(size_t)node*256 + c0];
    #pragma unroll
    for (int i=0;i<8;i++) acc[i] = dv * bf2f(s[i]);
  }
  int j0 = rowptr[node], j1 = rowptr[node+1];
  for (int base=j0; base<j1; base+=32){
    int n = j1 - base; n = n < 32 ? n : 32;
    int   myc = (sub < n) ? col[base+sub] : 0;
    float myd = (sub < n) ? dinv[myc]     : 0.f;
    for (int j=0;j<n;j++){
      int   s  = __shfl(myc, j, 32);
      float ds = __shfl(myd, j, 32);
      short8v nb = *(const short8v*)&Ab[(size_t)s*256 + c0];
      #pragma unroll
      for (int i=0;i<8;i++) acc[i] += ds * bf2f(nb[i]);
    }
  }
  float sum=0.f, sq=0.f;
  float o[8];
  #pragma unroll
  for (int i=0;i<8;i++){
    float v = dv*acc[i] + bvec[c0+i];
    o[i] = v;
    sum += v; sq += v*v;
  }
  uint4 ov;
  ov.x = pkbf(o[0],o[1]); ov.y = pkbf(o[2],o[3]);
  ov.z = pkbf(o[4],o[5]); ov.w = pkbf(o[6],o[7]);
  *(uint4*)&outU[(size_t)node*128 + sub*4] = ov;

  #pragma unroll
  for (int off=16; off>0; off>>=1){
    sum += __shfl_down(sum, off, 32);
    sq  += __shfl_down(sq,  off, 32);
  }
  __shared__ float ls1[8], ls2[8];
  if (sub==0){ ls1[threadIdx.x>>5]=sum; ls2[threadIdx.x>>5]=sq; }
  __syncthreads();
  if (threadIdx.x==0){
    float a=0.f, b=0.f;
    #pragma unroll
    for (int i=0;i<8;i++){ a+=ls1[i]; b+=ls2[i]; }
    partS[bid]=a; partQ[bid]=b;
  }
}

// ---------------- stats over 4096 per-block partials (double accum) ---------
__global__ void k_stats(const float* __restrict__ partS, const float* __restrict__ partQ,
                        float* __restrict__ stats){
  __shared__ double s1[1024], s2[1024];
  int t = threadIdx.x;
  double a=0.0, b=0.0;
  for (int i=t; i<4096; i+=1024){ a += (double)partS[i]; b += (double)partQ[i]; }
  s1[t]=a; s2[t]=b; __syncthreads();
  for (int off=512; off>0; off>>=1){
    if (t<off){ s1[t]+=s1[t+off]; s2[t]+=s2[t+off]; }
    __syncthreads();
  }
  if (t==0){
    double mean = s1[0] / (double)NP_;
    double var  = s2[0] / (double)NP_ - mean*mean;
    var = var > 0.0 ? var : 0.0;
    stats[0] = (float)mean;
    stats[1] = (float)(1.0 / (sqrt(var) + (double)EPS_));
  }
}

// ---------------- final norm + prelu (bf16 in, f32 out) ---------------------
__global__ __launch_bounds__(256) void k_norm_f32(const unsigned* __restrict__ inU,
    const float* __restrict__ g, const float* __restrict__ be,
    const float* __restrict__ aP, const float* __restrict__ stats,
    float* __restrict__ out){
  float mean = stats[0], inv = stats[1], a = aP[0];
  int gid   = blockIdx.x*256 + threadIdx.x;
  int base8 = gid*8;
  int c0    = base8 & (D_-1);
  uint4 vin = *(const uint4*)&inU[gid*4];
  float4 g0 = *(const float4*)&g[c0],  g1 = *(const float4*)&g[c0+4];
  float4 e0 = *(const float4*)&be[c0], e1 = *(const float4*)&be[c0+4];
  float v[8];
  unpack2(vin.x, v[0], v[1]); unpack2(vin.y, v[2], v[3]);
  unpack2(vin.z, v[4], v[5]); unpack2(vin.w, v[6], v[7]);
  float gg[8] = {g0.x,g0.y,g0.z,g0.w,g1.x,g1.y,g1.z,g1.w};
  float eb[8] = {e0.x,e0.y,e0.z,e0.w,e1.x,e1.y,e1.z,e1.w};
  f32x4 o0, o1;
  #pragma unroll
  for (int i=0;i<8;i++){
    float tt = gg[i]*((v[i]-mean)*inv) + eb[i];
    tt = tt>=0.f ? tt : a*tt;
    if (i<4) o0[i] = tt; else o1[i-4] = tt;
  }
  *(f32x4*)&out[base8]     = o0;
  *(f32x4*)&out[base8 + 4] = o1;
}

// ---------------- launch ----------------

extern "C" void kernel_launch(void* const* d_in, const int* in_sizes, int n_in,
                              void* d_out, int out_size, void* d_ws, size_t ws_size,
                              hipStream_t stream){
  const float* x    = (const float*)d_in[0];
  const int*   knn  = (const int*)  d_in[1];
  const void*  mask =               d_in[2];
  const float* W0   = (const float*)d_in[3];
  const float* b0   = (const float*)d_in[4];
  const float* g0   = (const float*)d_in[5];
  const float* be0  = (const float*)d_in[6];
  const float* a0   = (const float*)d_in[7];
  const float* W1   = (const float*)d_in[8];
  const float* b1   = (const float*)d_in[9];
  const float* g1   = (const float*)d_in[10];
  const float* be1  = (const float*)d_in[11];
  const float* a1   = (const float*)d_in[12];
  float* out = (float*)d_out;

  char* w = (char*)d_ws;
  size_t off = 0;
  auto alloc = [&](size_t bytes)->void*{
    void* p = w + off; off = (off + bytes + 255) & ~(size_t)255; return p;
  };
  int*      degcnt  = (int*)     alloc(NT_*4);
  int*      rowptr  = (int*)     alloc((NT_+1)*4);
  int*      fillptr = (int*)     alloc(NT_*4);
  int*      col     = (int*)     alloc(E16_*4);
  float*    dinv    = (float*)   alloc(NT_*4);
  float*    partS   = (float*)   alloc(4096*4);
  float*    partQ   = (float*)   alloc(4096*4);
  float*    stats   = (float*)   alloc(4*4);
  int*      flag    = (int*)     alloc(4);
  short*    Ab      = (short*)   alloc((size_t)NP_*2);   // gemm output (bf16)
  unsigned* Bagg    = (unsigned*)alloc((size_t)NP_*2);   // agg output (bf16 pairs)
  short*    Wt0     = (short*)   alloc(256*256*2);
  short*    Wt1     = (short*)   alloc(256*256*2);

  // prep (weights + degcnt zero + detect) -> deg -> scan
  hipLaunchKernelGGL(k_prep,  dim3(256),      dim3(256), 0, stream, W0, W1, Wt0, Wt1,
                     degcnt, (const unsigned int*)mask, flag);
  hipLaunchKernelGGL(k_deg,   dim3(E16_/256), dim3(256), 0, stream, knn, mask, flag, degcnt);
  hipLaunchKernelGGL(k_scan,  dim3(1),        dim3(1024),0, stream, degcnt, rowptr, fillptr, dinv);

  // layer 0: gemm (cvt_x fused) runs concurrently with CSR fill in one dispatch
  hipLaunchKernelGGL(k_gemm_x_fill, dim3(2560), dim3(256), 0, stream, x, Wt0, Ab,
                     knn, mask, flag, fillptr, col);
  hipLaunchKernelGGL(k_agg,    dim3(NT_/8),   dim3(256), 0, stream, Ab, rowptr, col, dinv, b0, Bagg, partS, partQ);
  hipLaunchKernelGGL(k_stats,  dim3(1),       dim3(1024),0, stream, partS, partQ, stats);

  // layer 1 (norm0+prelu fused into gemm staging)
  hipLaunchKernelGGL(k_gemm_n, dim3(512),     dim3(256), 0, stream, Bagg, g0, be0, a0, stats, Wt1, Ab);
  hipLaunchKernelGGL(k_agg,    dim3(NT_/8),   dim3(256), 0, stream, Ab, rowptr, col, dinv, b1, Bagg, partS, partQ);
  hipLaunchKernelGGL(k_stats,  dim3(1),       dim3(1024),0, stream, partS, partQ, stats);
  hipLaunchKernelGGL(k_norm_f32, dim3(NP_/2048), dim3(256), 0, stream, Bagg, g1, be1, a1, stats, out);
}